// Round 11
// baseline (831.773 us; speedup 1.0000x reference)
//
#include <hip/hip_runtime.h>
#include <hip/hip_bf16.h>

#define CI 192
#define LL_ 4096

__global__ __launch_bounds__(256) void k_zero(float* __restrict__ p, int n){
  int i = blockIdx.x*256 + threadIdx.x;
  if (i < n) p[i] = 0.f;
}

// ------------------------------------------------ K1: RMSNorm + in_proj (tiled GEMM, 48-o tiles)
__global__ __launch_bounds__(256) void k_rms_inproj(const float* __restrict__ x,
    const float* __restrict__ rmsw, const float* __restrict__ ipw,
    float* __restrict__ xc, float* __restrict__ zT){
  int og = blockIdx.x & 7; int lt = (blockIdx.x >> 3) & 63; int b = blockIdx.x >> 9;
  int l0 = lt << 6;
  __shared__ float xt[64][97];
  __shared__ float wt[96*48];
  __shared__ float rr[64];
  __shared__ float rw[96];
  int tid = threadIdx.x;
  for (int idx = tid; idx < 6144; idx += 256){ int r = idx/96, d = idx - r*96;
    xt[r][d] = x[((size_t)b*4096 + l0 + r)*96 + d]; }
  if (tid < 96) rw[tid] = rmsw[tid];
  int o0 = og*48;
  for (int idx = tid; idx < 4608; idx += 256){ int o = idx%48, d = idx/48;
    wt[d*48 + o] = ipw[(size_t)(o0 + o)*96 + d]; }
  __syncthreads();
  if (tid < 64){
    float s = 0.f;
    for (int d = 0; d < 96; d++){ float v = xt[tid][d]; s += v*v; }
    rr[tid] = rsqrtf(s*(1.0f/96.0f) + 1e-5f);
  }
  __syncthreads();
  for (int idx = tid; idx < 6144; idx += 256){ int r = idx/96, d = idx - r*96;
    xt[r][d] *= rr[r]*rw[d]; }
  __syncthreads();
  int l = tid & 63, grp = tid >> 6;
  float acc[12];
  #pragma unroll
  for (int j = 0; j < 12; j++) acc[j] = 0.f;
  for (int d = 0; d < 96; d++){
    float xv = xt[l][d];
    const float* wr = &wt[d*48 + grp*12];
    #pragma unroll
    for (int j = 0; j < 12; j += 4){
      float4 w4 = *(const float4*)&wr[j];
      acc[j]   += xv*w4.x; acc[j+1] += xv*w4.y;
      acc[j+2] += xv*w4.z; acc[j+3] += xv*w4.w;
    }
  }
  #pragma unroll
  for (int j = 0; j < 12; j++){
    int o = o0 + grp*12 + j;
    if (o < 192) xc[((size_t)b*192 + o)*4096 + l0 + l] = acc[j];
    else         zT[((size_t)b*192 + (o-192))*4096 + l0 + l] = acc[j];
  }
}

// ------------------------------------------------ K2: forward rfft2 (ortho) + fused Haar DWT
__global__ __launch_bounds__(256) void k_dft_fwd(const float* __restrict__ xc,
    float* __restrict__ fre, float* __restrict__ fim, float* __restrict__ fab,
    float* __restrict__ ll, float* __restrict__ lh, float* __restrict__ hl, float* __restrict__ hh){
  int plane = blockIdx.x;
  __shared__ float sxT[64*65];
  __shared__ float t1r[64*34], t1i[64*34];
  __shared__ float tabr[16], tabi[16];
  __shared__ float ct64[64], st64[64];
  int tid = threadIdx.x;
  const float* X = xc + (size_t)plane*4096;
  for (int i = tid; i < 4096; i += 256){ int h = i >> 6, w = i & 63; sxT[w*65 + h] = X[i]; }
  if (tid < 16){ tabr[tid] = cospif((float)tid/8.0f); tabi[tid] = -sinpif((float)tid/8.0f); }
  if (tid < 64){ ct64[tid] = cospif((float)tid/32.0f); st64[tid] = sinpif((float)tid/32.0f); }
  __syncthreads();
  {
    size_t qbase = (size_t)plane*1024;
    for (int idx = tid; idx < 1024; idx += 256){
      int y2 = idx >> 5, x2 = idx & 31;
      float a_ = sxT[(2*x2)*65 + 2*y2],     b_ = sxT[(2*x2+1)*65 + 2*y2];
      float c_ = sxT[(2*x2)*65 + 2*y2+1],   d_ = sxT[(2*x2+1)*65 + 2*y2+1];
      ll[qbase + idx] = (a_+b_+c_+d_)*0.5f; lh[qbase + idx] = (a_-b_+c_-d_)*0.5f;
      hl[qbase + idx] = (a_+b_-c_-d_)*0.5f; hh[qbase + idx] = (a_-b_-c_+d_)*0.5f;
    }
  }
  {
    int hp = tid & 31, g = tid >> 5;
    float a0r[4], a0i[4], a1r[4], a1i[4];
    #pragma unroll
    for (int j = 0; j < 4; j++){ a0r[j]=0.f; a0i[j]=0.f; a1r[j]=0.f; a1i[j]=0.f; }
    float s32_0 = 0.f, s32_1 = 0.f;
    for (int w = 0; w < 64; w++){
      float xv0 = sxT[w*65 + hp];
      float xv1 = sxT[w*65 + hp + 32];
      int m0 = (w*g) & 15;
      float twr = tabr[m0], twi = tabi[m0];
      int ms = w & 15;
      float str = tabr[ms], sti = tabi[ms];
      #pragma unroll
      for (int j = 0; j < 4; j++){
        a0r[j] += xv0*twr; a0i[j] += xv0*twi;
        a1r[j] += xv1*twr; a1i[j] += xv1*twi;
        float nr = twr*str - twi*sti;
        float ni = twr*sti + twi*str;
        twr = nr; twi = ni;
      }
      if (g == 0){ float sg = (w & 1) ? -1.f : 1.f; s32_0 += xv0*sg; s32_1 += xv1*sg; }
    }
    #pragma unroll
    for (int j = 0; j < 4; j++){
      int k = 4*g + j;
      t1r[hp*34 + k] = a0r[j];        t1i[hp*34 + k] = a0i[j];
      t1r[(hp+32)*34 + k] = a1r[j];   t1i[(hp+32)*34 + k] = a1i[j];
    }
    if (g == 0){
      t1r[hp*34 + 32] = s32_0;      t1i[hp*34 + 32] = 0.f;
      t1r[(hp+32)*34 + 32] = s32_1; t1i[(hp+32)*34 + 32] = 0.f;
    }
  }
  __syncthreads();
  {
    int fp = tid & 31, g = tid >> 5;
    float stepr = cospif((float)fp/32.0f), stepi = -sinpif((float)fp/32.0f);
    float a0r[4], a0i[4], a1r[4], a1i[4];
    #pragma unroll
    for (int j = 0; j < 4; j++){ a0r[j]=0.f; a0i[j]=0.f; a1r[j]=0.f; a1i[j]=0.f; }
    float b0r=0.f, b0i=0.f, b1r=0.f, b1i=0.f;
    for (int hb = 0; hb < 4; hb++){
      int m = ((hb*16)*fp) & 63;
      float twr = ct64[m], twi = -st64[m];
      for (int hh2 = 0; hh2 < 16; hh2++){
        int h = hb*16 + hh2;
        float sg = (h & 1) ? -1.f : 1.f;
        #pragma unroll
        for (int j = 0; j < 4; j++){
          float Tr = t1r[h*34 + 4*g + j], Ti = t1i[h*34 + 4*g + j];
          float pr = Tr*twr - Ti*twi;
          float pi = Tr*twi + Ti*twr;
          a0r[j] += pr; a0i[j] += pi;
          a1r[j] += sg*pr; a1i[j] += sg*pi;
        }
        if (g == 0){
          float Tr = t1r[h*34 + 32], Ti = t1i[h*34 + 32];
          float pr = Tr*twr - Ti*twi, pi = Tr*twi + Ti*twr;
          b0r += pr; b0i += pi; b1r += sg*pr; b1i += sg*pi;
        }
        float nr = twr*stepr - twi*stepi, ni = twr*stepi + twi*stepr;
        twr = nr; twi = ni;
      }
    }
    size_t base = (size_t)plane*2112;
    #pragma unroll
    for (int j = 0; j < 4; j++){
      int k = 4*g + j;
      float r0 = a0r[j]*(1.f/64.f), i0 = a0i[j]*(1.f/64.f);
      float r1 = a1r[j]*(1.f/64.f), i1 = a1i[j]*(1.f/64.f);
      fre[base + fp*33 + k] = r0; fim[base + fp*33 + k] = i0;
      fab[base + fp*33 + k] = sqrtf(r0*r0 + i0*i0);
      fre[base + (fp+32)*33 + k] = r1; fim[base + (fp+32)*33 + k] = i1;
      fab[base + (fp+32)*33 + k] = sqrtf(r1*r1 + i1*i1);
    }
    if (g == 0){
      float r0 = b0r*(1.f/64.f), i0 = b0i*(1.f/64.f);
      float r1 = b1r*(1.f/64.f), i1 = b1i*(1.f/64.f);
      fre[base + fp*33 + 32] = r0; fim[base + fp*33 + 32] = i0;
      fab[base + fp*33 + 32] = sqrtf(r0*r0 + i0*i0);
      fre[base + (fp+32)*33 + 32] = r1; fim[base + (fp+32)*33 + 32] = i1;
      fab[base + (fp+32)*33 + 32] = sqrtf(r1*r1 + i1*i1);
    }
  }
}

// ------------------------------------------------ K3: m = gelu(W1 @ |xf| + b1), scalar weights
__global__ __launch_bounds__(256) void k_cmix1(const float* __restrict__ fab,
    const float* __restrict__ w1, const float* __restrict__ b1, float* __restrict__ m){
  int bid = blockIdx.x;
  int pt = bid % 9; int og = (bid/9) % 24; int b = bid/216;
  int tid = threadIdx.x;
  int p = pt*256 + tid; bool act = p < 2112;
  float acc[8];
  #pragma unroll
  for (int o = 0; o < 8; o++) acc[o] = b1[og*8 + o];
  const float* xb = fab + (size_t)b*CI*2112 + p;
  const float* w0 = w1 + (size_t)(og*8)*192;
  for (int c = 0; c < 192; c++){
    float xv = act ? xb[(size_t)c*2112] : 0.f;
    acc[0] += xv*w0[c];
    acc[1] += xv*w0[192 + c];
    acc[2] += xv*w0[384 + c];
    acc[3] += xv*w0[576 + c];
    acc[4] += xv*w0[768 + c];
    acc[5] += xv*w0[960 + c];
    acc[6] += xv*w0[1152 + c];
    acc[7] += xv*w0[1344 + c];
  }
  if (act){
    #pragma unroll
    for (int o = 0; o < 8; o++){
      float a = acc[o];
      m[((size_t)b*192 + og*8 + o)*2112 + p] = 0.5f*a*(1.0f + erff(a*0.70710678118654752f));
    }
  }
}

// ------------------------------------------------ K4: mag = W2 @ m + b2; in-place, scalar weights
__global__ __launch_bounds__(256) void k_cmix2(const float* __restrict__ m,
    const float* __restrict__ w2, const float* __restrict__ bi2,
    float* __restrict__ fre, float* __restrict__ fim, const float* __restrict__ fab){
  int bid = blockIdx.x;
  int pt = bid % 9; int og = (bid/9) % 24; int b = bid/216;
  int tid = threadIdx.x;
  int p = pt*256 + tid; bool act = p < 2112;
  float acc[8];
  #pragma unroll
  for (int o = 0; o < 8; o++) acc[o] = bi2[og*8 + o];
  const float* xb = m + (size_t)b*CI*2112 + p;
  const float* w0 = w2 + (size_t)(og*8)*192;
  for (int c = 0; c < 192; c++){
    float xv = act ? xb[(size_t)c*2112] : 0.f;
    acc[0] += xv*w0[c];
    acc[1] += xv*w0[192 + c];
    acc[2] += xv*w0[384 + c];
    acc[3] += xv*w0[576 + c];
    acc[4] += xv*w0[768 + c];
    acc[5] += xv*w0[960 + c];
    acc[6] += xv*w0[1152 + c];
    acc[7] += xv*w0[1344 + c];
  }
  if (act){
    #pragma unroll
    for (int o = 0; o < 8; o++){
      size_t id = ((size_t)b*192 + og*8 + o)*2112 + p;
      float ab = fab[id];
      float re, im;
      if (ab > 1e-30f){ float sc = acc[o]/ab; re = sc*fre[id]; im = sc*fim[id]; }
      else { re = acc[o]; im = 0.f; }
      fre[id] = re; fim[id] = im;
    }
  }
}

// ------------------------------------------------ K6: full 3x3 conv — v5: full-image, 4-px vertical strips
__global__ __launch_bounds__(256) void k_wconv(const float* __restrict__ in,
    const float* __restrict__ ww, float* __restrict__ wpart){
  int bid = blockIdx.x;
  int og = bid / 36;                 // 0..23 (8 oc each)
  int img = bid % 36;                // b + t*4 + cs*12
  int b = img & 3; int t = (img >> 2) % 3; int cs = img / 12;
  int o0 = og*8, c0 = cs*64;
  const float* inb = in + (size_t)t*786432 + (size_t)b*196608;
  float* outb = wpart + (size_t)cs*2359296 + (size_t)t*786432 + (size_t)b*196608;
  __shared__ float wl[64*72];        // [icl][q][oc8]  18.4 KB
  __shared__ float pimg[2][1156];    // padded 34x34   9.2 KB
  int tid = threadIdx.x;
  for (int idx = tid; idx < 4608; idx += 256){
    int q = idx % 9; int icl = (idx/9) & 63; int ocl = idx/576;
    wl[icl*72 + q*8 + ocl] = ww[((size_t)(o0 + ocl)*192 + c0 + icl)*9 + q];
  }
  for (int idx = tid; idx < 1156; idx += 256){
    int row = idx/34, col = idx - row*34;
    int yg = row - 1, xg = col - 1;
    pimg[0][idx] = (yg >= 0 && yg < 32 && xg >= 0 && xg < 32)
                   ? inb[(size_t)c0*1024 + yg*32 + xg] : 0.f;
  }
  __syncthreads();
  int x = tid & 31, rg = tid >> 5;   // output rows 4rg..4rg+3, col x
  float acc[4][8];
  #pragma unroll
  for (int p = 0; p < 4; p++)
    #pragma unroll
    for (int o = 0; o < 8; o++) acc[p][o] = 0.f;
  int cur = 0;
  for (int icl = 0; icl < 64; icl++){
    float pf[5];
    #pragma unroll
    for (int s = 0; s < 5; s++) pf[s] = 0.f;
    if (icl + 1 < 64){
      int cn = c0 + icl + 1;
      #pragma unroll
      for (int s = 0; s < 5; s++){
        int idx = tid + s*256;
        if (idx < 1156){
          int row = idx/34, col = idx - row*34;
          int yg = row - 1, xg = col - 1;
          pf[s] = (yg >= 0 && yg < 32 && xg >= 0 && xg < 32)
                  ? inb[(size_t)cn*1024 + yg*32 + xg] : 0.f;
        }
      }
    }
    // 6x3 window: LDS rows 4rg..4rg+5 (image rows 4rg-1..4rg+4), cols x..x+2 — conflict-free
    float win[6][3];
    #pragma unroll
    for (int rr = 0; rr < 6; rr++){
      int off = (4*rg + rr)*34 + x;
      win[rr][0] = pimg[cur][off];
      win[rr][1] = pimg[cur][off + 1];
      win[rr][2] = pimg[cur][off + 2];
    }
    const float* wbase = &wl[icl*72];
    #pragma unroll
    for (int q = 0; q < 9; q++){
      int ky = q/3, kx = q%3;
      const float4* wq = (const float4*)&wbase[q*8];
      float4 wA = wq[0], wB = wq[1];
      #pragma unroll
      for (int p = 0; p < 4; p++){
        float v = win[p + ky][kx];
        acc[p][0] += v*wA.x; acc[p][1] += v*wA.y; acc[p][2] += v*wA.z; acc[p][3] += v*wA.w;
        acc[p][4] += v*wB.x; acc[p][5] += v*wB.y; acc[p][6] += v*wB.z; acc[p][7] += v*wB.w;
      }
    }
    if (icl + 1 < 64){
      #pragma unroll
      for (int s = 0; s < 5; s++){
        int idx = tid + s*256;
        if (idx < 1156) pimg[cur ^ 1][idx] = pf[s];
      }
    }
    __syncthreads();
    cur ^= 1;
  }
  #pragma unroll
  for (int o = 0; o < 8; o++)
    #pragma unroll
    for (int p = 0; p < 4; p++)
      outb[(size_t)(o0 + o)*1024 + (4*rg + p)*32 + x] = acc[p][o];
}

// ------------------------------------------------ K7 (fused): irfft2 + combine + depthwise3x3 + SiLU -> ab, aT
__global__ __launch_bounds__(256) void k_ifwd(const float* __restrict__ fre2,
    const float* __restrict__ fim2, const float* __restrict__ xc,
    const float* __restrict__ ll, const float* __restrict__ wpart, const float* __restrict__ wb,
    const float* __restrict__ dww, const float* __restrict__ dwb,
    float* __restrict__ ab, float* __restrict__ aT){
  int plane = blockIdx.x;
  int c = plane % 192;
  __shared__ float sm[12936];
  float* gr  = sm;
  float* gi  = sm + 2176;
  float* ur  = sm + 4352;
  float* ui  = sm + 6528;
  float* sx2 = sm + 8704;
  float* t64r = sm + 12800; float* t64i = sm + 12864;
  float* t4r  = sm + 12928; float* t4i  = sm + 12932;
  float* scratch = sm;
  int tid = threadIdx.x;
  for (int i = tid; i < 2112; i += 256){
    size_t o = (size_t)plane*2112 + i;
    int f = i/33, k = i - f*33;
    gr[f*34 + k] = fre2[o]; gi[f*34 + k] = fim2[o];
  }
  if (tid < 64){ t64r[tid] = cospif((float)tid/32.0f); t64i[tid] = sinpif((float)tid/32.0f); }
  if (tid < 4){ t4r[tid] = (tid == 0) ? 1.f : ((tid == 2) ? -1.f : 0.f);
                t4i[tid] = (tid == 1) ? 1.f : ((tid == 3) ? -1.f : 0.f); }
  __syncthreads();
  {
    int hp = tid & 31, g = tid >> 5;
    float stepr = cospif((float)hp/32.0f), stepi = sinpif((float)hp/32.0f);
    float a0r[4], a0i[4], a1r[4], a1i[4];
    #pragma unroll
    for (int j = 0; j < 4; j++){ a0r[j]=0.f; a0i[j]=0.f; a1r[j]=0.f; a1i[j]=0.f; }
    float b0r=0.f, b0i=0.f, b1r=0.f, b1i=0.f;
    for (int fb = 0; fb < 4; fb++){
      int m = ((fb*16)*hp) & 63;
      float twr = t64r[m], twi = t64i[m];
      for (int ff = 0; ff < 16; ff++){
        int f = fb*16 + ff;
        float sg = (f & 1) ? -1.f : 1.f;
        #pragma unroll
        for (int j = 0; j < 4; j++){
          float Gr = gr[f*34 + 4*g + j], Gi = gi[f*34 + 4*g + j];
          float pr = Gr*twr - Gi*twi;
          float pi = Gr*twi + Gi*twr;
          a0r[j] += pr; a0i[j] += pi;
          a1r[j] += sg*pr; a1i[j] += sg*pi;
        }
        if (g == 0){
          float Gr = gr[f*34 + 32], Gi = gi[f*34 + 32];
          float pr = Gr*twr - Gi*twi, pi = Gr*twi + Gi*twr;
          b0r += pr; b0i += pi; b1r += sg*pr; b1i += sg*pi;
        }
        float nr = twr*stepr - twi*stepi, ni = twr*stepi + twi*stepr;
        twr = nr; twi = ni;
      }
    }
    __syncthreads();
    #pragma unroll
    for (int j = 0; j < 4; j++){
      int k = 4*g + j;
      float ck = (k == 0) ? (1.f/64.f) : (2.f/64.f);
      ur[hp*34 + k] = a0r[j]*ck;       ui[hp*34 + k] = a0i[j]*ck;
      ur[(hp+32)*34 + k] = a1r[j]*ck;  ui[(hp+32)*34 + k] = a1i[j]*ck;
    }
    if (g == 0){
      ur[hp*34 + 32] = b0r*(1.f/64.f);      ui[hp*34 + 32] = b0i*(1.f/64.f);
      ur[(hp+32)*34 + 32] = b1r*(1.f/64.f); ui[(hp+32)*34 + 32] = b1i*(1.f/64.f);
    }
  }
  __syncthreads();
  {
    int h = tid & 63, wg = tid >> 6;
    float acc[16];
    #pragma unroll
    for (int j = 0; j < 16; j++) acc[j] = 0.f;
    for (int k = 0; k <= 32; k++){
      float Ur = ur[h*34 + k], Ui = ui[h*34 + k];
      int m = (k*wg) & 3;
      float twr = t4r[m], twi = t4i[m];
      float str = t64r[k], sti = t64i[k];
      #pragma unroll
      for (int j = 0; j < 16; j++){
        acc[j] += Ur*twr - Ui*twi;
        float nr = twr*str - twi*sti, ni = twr*sti + twi*str;
        twr = nr; twi = ni;
      }
    }
    #pragma unroll
    for (int j = 0; j < 16; j++) sx2[h*64 + 16*wg + j] = acc[j];
  }
  __syncthreads();
  float bia = wb[c];
  for (int p = tid; p < 4096; p += 256){
    int h = p >> 6, w = p & 63;
    size_t q = (size_t)plane*1024 + (size_t)(h >> 1)*32 + (w >> 1);
    float LLv = ll[q];
    float LH = wpart[q]           + wpart[2359296 + q]           + wpart[4718592 + q]           + bia;
    float HL = wpart[786432 + q]  + wpart[2359296 + 786432 + q]  + wpart[4718592 + 786432 + q]  + bia;
    float HH = wpart[1572864 + q] + wpart[2359296 + 1572864 + q] + wpart[4718592 + 1572864 + q] + bia;
    float v;
    bool hb = (h & 1), wbit = (w & 1);
    if (!hb && !wbit)      v = (LLv + LH + HL + HH)*0.5f;
    else if (!hb && wbit)  v = (LLv - LH + HL - HH)*0.5f;
    else if (hb && !wbit)  v = (LLv + LH - HL - HH)*0.5f;
    else                   v = (LLv - LH - HL + HH)*0.5f;
    sx2[p] = 2.0f*xc[(size_t)plane*4096 + p] + sx2[p] + v;
  }
  __syncthreads();
  float wk[9];
  #pragma unroll
  for (int q = 0; q < 9; q++) wk[q] = dww[c*9 + q];
  float dbv = dwb[c];
  for (int p = tid; p < 4096; p += 256){
    int h = p >> 6, w = p & 63;
    float acc = dbv;
    #pragma unroll
    for (int ky = 0; ky < 3; ky++){
      int yy = h + ky - 1; if (yy < 0 || yy > 63) continue;
      #pragma unroll
      for (int kx = 0; kx < 3; kx++){
        int xx = w + kx - 1; if (xx < 0 || xx > 63) continue;
        acc += sx2[yy*64 + xx]*wk[ky*3 + kx];
      }
    }
    scratch[h*65 + w] = acc / (1.f + __expf(-acc));
  }
  __syncthreads();
  float* abp = ab + (size_t)plane*4096;
  float* aTp = aT + (size_t)plane*4096;
  for (int p = tid; p < 4096; p += 256){
    abp[p] = scratch[(p >> 6)*65 + (p & 63)];
    aTp[p] = scratch[(p & 63)*65 + (p >> 6)];
  }
}

// ------------------------------------------------ K10: x_proj; wave-split GEMM
__global__ __launch_bounds__(256) void k_xproj(const float* __restrict__ ab,
    const float* __restrict__ aT, const float* __restrict__ xpw,
    float* __restrict__ Bsb, float* __restrict__ Csb, float* __restrict__ dlsb,
    float* __restrict__ xsb){
  int bid = blockIdx.x;
  int s = bid & 63; int k = (bid >> 6) & 3; int b = bid >> 8;
  int tid = threadIdx.x;
  __shared__ float als[192][65];
  __shared__ float dls[6][64];
  int l0 = s << 6;
  const float* src = (k & 1) ? aT : ab;
  int off0 = (k < 2) ? l0 : (4095 - l0);
  int stp  = (k < 2) ? 1 : -1;
  for (int idx = tid; idx < 192*64; idx += 256){
    int d = idx >> 6, i = idx & 63;
    als[d][i] = src[((size_t)b*192 + d)*4096 + off0 + stp*i];
  }
  __syncthreads();
  {
    int i = tid & 63, wg = tid >> 6;
    const float* wr[10];
    #pragma unroll
    for (int r = 0; r < 10; r++){
      int cp = wg + 4*r; if (cp > 37) cp = 37;
      wr[r] = xpw + ((size_t)k*38 + cp)*192;
    }
    float acc[10];
    #pragma unroll
    for (int r = 0; r < 10; r++) acc[r] = 0.f;
    for (int d = 0; d < 192; d++){
      float v = als[d][i];
      #pragma unroll
      for (int r = 0; r < 10; r++) acc[r] += v*wr[r][d];
    }
    #pragma unroll
    for (int r = 0; r < 10; r++){
      int cp = wg + 4*r;
      if (cp > 37) continue;
      if (cp < 6) dls[cp][i] = acc[r];
      else if (cp < 22) Bsb[((size_t)(b*4 + k)*16 + (cp - 6 ))*4096 + l0 + i] = acc[r];
      else              Csb[((size_t)(b*4 + k)*16 + (cp - 22))*4096 + l0 + i] = acc[r];
    }
  }
  size_t xbase = ((size_t)(b*4 + k)*4096 + l0)*192;
  for (int j = tid; j < 192*64; j += 256){
    int i = j / 192, c = j % 192;
    xsb[xbase + (size_t)i*192 + c] = als[c][i];
  }
  __syncthreads();
  size_t dbase = (size_t)((b*4 + k)*64 + s)*384;
  for (int j = tid; j < 384; j += 256){
    int i = j/6, r = j - i*6;
    dlsb[dbase + j] = dls[r][i];
  }
}

// ------------------------------------------------ K11: scan phase A (fast-exp)
__global__ __launch_bounds__(192) void k_scanA(const float* __restrict__ xsb,
    const float* __restrict__ dlsb, const float* __restrict__ Bsb,
    const float* __restrict__ dtw, const float* __restrict__ dtb,
    const float* __restrict__ alog, float* __restrict__ Pb, float* __restrict__ Qb){
  int bid = blockIdx.x; int s = bid & 63; int k = (bid >> 6) & 3; int b = bid >> 8;
  int c = threadIdx.x; int bk = b*4 + k;
  __shared__ float sdl[384];
  __shared__ float sB[16][64];
  size_t dbase = (size_t)(bk*64 + s)*384;
  for (int j = c; j < 384; j += 192) sdl[j] = dlsb[dbase + j];
  for (int j = c; j < 1024; j += 192){ int n = j >> 6, i = j & 63;
    sB[n][i] = Bsb[((size_t)bk*16 + n)*4096 + (s << 6) + i]; }
  __syncthreads();
  float A[16], P[16], Q[16];
  const float* arow = alog + ((size_t)k*192 + c)*16;
  bool fast = true;
  #pragma unroll
  for (int n = 0; n < 16; n++){
    A[n] = -__expf(arow[n]); P[n] = 1.f; Q[n] = 0.f;
    if (fabsf(A[n] + (float)(n+1)) > 1e-3f) fast = false;
  }
  float dw[6];
  #pragma unroll
  for (int r = 0; r < 6; r++) dw[r] = dtw[((size_t)k*192 + c)*6 + r];
  float db = dtb[k*192 + c];
  const float* xrow = xsb + ((size_t)bk*4096 + (s << 6))*192 + c;
  if (fast){
    for (int i = 0; i < 64; i++){
      float u = xrow[(size_t)i*192];
      float acc = db;
      #pragma unroll
      for (int r = 0; r < 6; r++) acc += sdl[i*6 + r]*dw[r];
      float dl = fmaxf(acc, 0.f) + log1pf(__expf(-fabsf(acc)));
      float du = dl*u;
      float e1 = __expf(-dl), e = 1.f;
      #pragma unroll
      for (int n = 0; n < 16; n++){
        e *= e1;
        P[n] *= e;
        Q[n] = Q[n]*e + du*sB[n][i];
      }
    }
  } else {
    for (int i = 0; i < 64; i++){
      float u = xrow[(size_t)i*192];
      float acc = db;
      #pragma unroll
      for (int r = 0; r < 6; r++) acc += sdl[i*6 + r]*dw[r];
      float dl = fmaxf(acc, 0.f) + log1pf(__expf(-fabsf(acc)));
      float du = dl*u;
      #pragma unroll
      for (int n = 0; n < 16; n++){
        float e = __expf(dl*A[n]);
        P[n] *= e;
        Q[n] = Q[n]*e + du*sB[n][i];
      }
    }
  }
  size_t pbase = ((size_t)(bk*64 + s)*16)*192 + c;
  #pragma unroll
  for (int n = 0; n < 16; n++){ Pb[pbase + (size_t)n*192] = P[n]; Qb[pbase + (size_t)n*192] = Q[n]; }
}

// ------------------------------------------------ K12: scan phase B (hin in-place over Pb)
__global__ __launch_bounds__(256) void k_scanB(float* __restrict__ Pb,
    const float* __restrict__ Qb){
  int id = blockIdx.x*256 + threadIdx.x;
  int c = id % 192; int rest = id / 192; int n = rest % 16; int bk = rest / 16;
  float h = 0.f;
  for (int s = 0; s < 64; s++){
    size_t o = (((size_t)bk*64 + s)*16 + n)*192 + c;
    float P = Pb[o], Q = Qb[o];
    Pb[o] = h;
    h = P*h + Q;
  }
}

// ------------------------------------------------ K13a: scan phase C — non-atomic (fast-exp)
__global__ __launch_bounds__(192) void k_scanC_buf(const float* __restrict__ xsb,
    const float* __restrict__ dlsb, const float* __restrict__ Bsb, const float* __restrict__ Csb,
    const float* __restrict__ hinb, const float* __restrict__ dtw, const float* __restrict__ dtb,
    const float* __restrict__ alog, const float* __restrict__ Dsp, float* __restrict__ Y){
  int bid = blockIdx.x; int s = bid & 63; int k = (bid >> 6) & 3; int b = bid >> 8;
  int c = threadIdx.x; int bk = b*4 + k;
  __shared__ float sdl[384];
  __shared__ float sB[16][64];
  __shared__ float sC[16][64];
  size_t dbase = (size_t)(bk*64 + s)*384;
  for (int j = c; j < 384; j += 192) sdl[j] = dlsb[dbase + j];
  for (int j = c; j < 1024; j += 192){ int n = j >> 6, i = j & 63;
    size_t o = ((size_t)bk*16 + n)*4096 + (s << 6) + i;
    sB[n][i] = Bsb[o]; sC[n][i] = Csb[o]; }
  __syncthreads();
  float A[16], h[16];
  const float* arow = alog + ((size_t)k*192 + c)*16;
  bool fast = true;
  #pragma unroll
  for (int n = 0; n < 16; n++){
    A[n] = -__expf(arow[n]);
    if (fabsf(A[n] + (float)(n+1)) > 1e-3f) fast = false;
  }
  size_t hbase = ((size_t)(bk*64 + s)*16)*192 + c;
  #pragma unroll
  for (int n = 0; n < 16; n++) h[n] = hinb[hbase + (size_t)n*192];
  float dw[6];
  #pragma unroll
  for (int r = 0; r < 6; r++) dw[r] = dtw[((size_t)k*192 + c)*6 + r];
  float db = dtb[k*192 + c];
  float Dc = Dsp[k*192 + c];
  const float* xrow = xsb + ((size_t)bk*4096 + (s << 6))*192 + c;
  int p0, pst;
  if (k == 0){ p0 = s << 6;        pst = 1;  }
  else if (k == 1){ p0 = s;        pst = 64; }
  else if (k == 2){ p0 = 4095 - (s << 6); pst = -1; }
  else { p0 = 4095 - s;            pst = -64; }
  float* Yk = Y + (((size_t)k*4 + b)*4096)*192;
  if (fast){
    for (int i = 0; i < 64; i++){
      float u = xrow[(size_t)i*192];
      float acc = db;
      #pragma unroll
      for (int r = 0; r < 6; r++) acc += sdl[i*6 + r]*dw[r];
      float dl = fmaxf(acc, 0.f) + log1pf(__expf(-fabsf(acc)));
      float du = dl*u;
      float e1 = __expf(-dl), e = 1.f;
      float y = 0.f;
      #pragma unroll
      for (int n = 0; n < 16; n++){
        e *= e1;
        h[n] = h[n]*e + du*sB[n][i];
        y += h[n]*sC[n][i];
      }
      Yk[(size_t)(p0 + pst*i)*192 + c] = y + u*Dc;
    }
  } else {
    for (int i = 0; i < 64; i++){
      float u = xrow[(size_t)i*192];
      float acc = db;
      #pragma unroll
      for (int r = 0; r < 6; r++) acc += sdl[i*6 + r]*dw[r];
      float dl = fmaxf(acc, 0.f) + log1pf(__expf(-fabsf(acc)));
      float du = dl*u;
      float y = 0.f;
      #pragma unroll
      for (int n = 0; n < 16; n++){
        float e = __expf(dl*A[n]);
        h[n] = h[n]*e + du*sB[n][i];
        y += h[n]*sC[n][i];
      }
      Yk[(size_t)(p0 + pst*i)*192 + c] = y + u*Dc;
    }
  }
}

// ------------------------------------------------ K13b: scan phase C — atomic fallback (fast-exp)
__global__ __launch_bounds__(192) void k_scanC_atom(const float* __restrict__ xsb,
    const float* __restrict__ dlsb, const float* __restrict__ Bsb, const float* __restrict__ Csb,
    const float* __restrict__ hinb, const float* __restrict__ dtw, const float* __restrict__ dtb,
    const float* __restrict__ alog, const float* __restrict__ Dsp, float* __restrict__ yb){
  int bid = blockIdx.x; int s = bid & 63; int k = (bid >> 6) & 3; int b = bid >> 8;
  int c = threadIdx.x; int bk = b*4 + k;
  __shared__ float sdl[384];
  __shared__ float sB[16][64];
  __shared__ float sC[16][64];
  size_t dbase = (size_t)(bk*64 + s)*384;
  for (int j = c; j < 384; j += 192) sdl[j] = dlsb[dbase + j];
  for (int j = c; j < 1024; j += 192){ int n = j >> 6, i = j & 63;
    size_t o = ((size_t)bk*16 + n)*4096 + (s << 6) + i;
    sB[n][i] = Bsb[o]; sC[n][i] = Csb[o]; }
  __syncthreads();
  float A[16], h[16];
  const float* arow = alog + ((size_t)k*192 + c)*16;
  bool fast = true;
  #pragma unroll
  for (int n = 0; n < 16; n++){
    A[n] = -__expf(arow[n]);
    if (fabsf(A[n] + (float)(n+1)) > 1e-3f) fast = false;
  }
  size_t hbase = ((size_t)(bk*64 + s)*16)*192 + c;
  #pragma unroll
  for (int n = 0; n < 16; n++) h[n] = hinb[hbase + (size_t)n*192];
  float dw[6];
  #pragma unroll
  for (int r = 0; r < 6; r++) dw[r] = dtw[((size_t)k*192 + c)*6 + r];
  float db = dtb[k*192 + c];
  float Dc = Dsp[k*192 + c];
  const float* xrow = xsb + ((size_t)bk*4096 + (s << 6))*192 + c;
  int p0, pst;
  if (k == 0){ p0 = s << 6;        pst = 1;  }
  else if (k == 1){ p0 = s;        pst = 64; }
  else if (k == 2){ p0 = 4095 - (s << 6); pst = -1; }
  else { p0 = 4095 - s;            pst = -64; }
  for (int i = 0; i < 64; i++){
    float u = xrow[(size_t)i*192];
    float acc = db;
    #pragma unroll
    for (int r = 0; r < 6; r++) acc += sdl[i*6 + r]*dw[r];
    float dl = fmaxf(acc, 0.f) + log1pf(__expf(-fabsf(acc)));
    float du = dl*u;
    float y = 0.f;
    if (fast){
      float e1 = __expf(-dl), e = 1.f;
      #pragma unroll
      for (int n = 0; n < 16; n++){
        e *= e1;
        h[n] = h[n]*e + du*sB[n][i];
        y += h[n]*sC[n][i];
      }
    } else {
      #pragma unroll
      for (int n = 0; n < 16; n++){
        float e = __expf(dl*A[n]);
        h[n] = h[n]*e + du*sB[n][i];
        y += h[n]*sC[n][i];
      }
    }
    y += u*Dc;
    atomicAdd(&yb[((size_t)b*4096 + p0 + pst*i)*192 + c], y);
  }
}

// ------------------------------------------------ K14b: symmetry enhance (atomic path)
__global__ __launch_bounds__(256) void k_enh(const float* __restrict__ yb,
    const float* __restrict__ symw, float* __restrict__ yfb){
  int id = blockIdx.x*256 + threadIdx.x;
  int c = id % 192; int rest = id / 192; int l = rest & 4095; int b = rest >> 12;
  int w = l & 63; int lr = (l | 63) - w;
  float v  = yb[id];
  float vr = yb[(((size_t)b << 12) + lr)*192 + c];
  float wg = 1.f/(1.f + __expf(-symw[0]));
  float enh = v*(1.f - wg) + 0.5f*(v + vr)*wg;
  yfb[id] = v + 0.2f*enh;
}

// ------------------------------------------------ K15a (fused, bigws)
__global__ __launch_bounds__(256) void k_final_comb(const float* __restrict__ Y,
    const float* __restrict__ symw, const float* __restrict__ zT,
    const float* __restrict__ g, const float* __restrict__ bta,
    const float* __restrict__ opw, const float* __restrict__ x, float* __restrict__ out){
  int og = blockIdx.x & 1; int lt = (blockIdx.x >> 1) & 127; int b = blockIdx.x >> 8;
  int l0 = lt << 5;
  __shared__ float sv[32][193];
  __shared__ float wt[192*48];
  __shared__ float sg[192], sb2[192];
  __shared__ float smu[32], srs[32];
  int tid = threadIdx.x;
  const size_t S = (size_t)4096*192;
  float wg = 1.f/(1.f + __expf(-symw[0]));
  for (int idx = tid; idx < 6144; idx += 256){
    int r = idx/192, cc = idx - r*192;
    int l = l0 + r; int w = l & 63; int lr = (l | 63) - w;
    size_t base = (size_t)b*S + cc;
    size_t o1 = base + (size_t)l*192, o2 = base + (size_t)lr*192;
    float v  = Y[o1] + Y[4*S + o1] + Y[8*S + o1] + Y[12*S + o1];
    float vr = Y[o2] + Y[4*S + o2] + Y[8*S + o2] + Y[12*S + o2];
    float enh = v*(1.f - wg) + 0.5f*(v + vr)*wg;
    sv[r][cc] = v + 0.2f*enh;
  }
  if (tid < 192){ sg[tid] = g[tid]; sb2[tid] = bta[tid]; }
  int o0 = og*48;
  for (int idx = tid; idx < 9216; idx += 256){ int o = idx % 48, c = idx/48;
    wt[c*48 + o] = opw[(size_t)(o0 + o)*192 + c]; }
  __syncthreads();
  if (tid < 32){
    float s1 = 0.f, s2 = 0.f;
    for (int c = 0; c < 192; c++){ float v = sv[tid][c]; s1 += v; s2 += v*v; }
    float mu = s1*(1.0f/192.0f);
    smu[tid] = mu; srs[tid] = rsqrtf(s2*(1.0f/192.0f) - mu*mu + 1e-5f);
  }
  __syncthreads();
  for (int idx = tid; idx < 6144; idx += 256){ int l = idx & 31, c = idx >> 5;
    float zv = zT[((size_t)b*192 + c)*4096 + l0 + l];
    float v = sv[l][c];
    float yn = (v - smu[l])*srs[l]*sg[c] + sb2[c];
    sv[l][c] = yn * (zv/(1.f + __expf(-zv)));
  }
  __syncthreads();
  int l = tid & 31, grp = tid >> 5;
  float acc[6];
  #pragma unroll
  for (int j = 0; j < 6; j++) acc[j] = 0.f;
  for (int c = 0; c < 192; c++){
    float svv = sv[l][c];
    const float* wr = &wt[c*48 + grp*6];
    #pragma unroll
    for (int j = 0; j < 6; j += 2){
      float2 w2 = *(const float2*)&wr[j];
      acc[j]   += svv*w2.x; acc[j+1] += svv*w2.y;
    }
  }
  size_t ob = ((size_t)b*4096 + l0 + l)*96 + o0 + grp*6;
  #pragma unroll
  for (int j = 0; j < 6; j++) acc[j] += x[ob + j];
  #pragma unroll
  for (int j = 0; j < 6; j += 2){
    float2 v2; v2.x = acc[j]; v2.y = acc[j+1];
    *(float2*)&out[ob + j] = v2;
  }
}

// ------------------------------------------------ K15b: fallback
__global__ __launch_bounds__(256) void k_final(const float* __restrict__ yf,
    const float* __restrict__ zT, const float* __restrict__ g, const float* __restrict__ bta,
    const float* __restrict__ opw, const float* __restrict__ x, float* __restrict__ out){
  int og = blockIdx.x & 1; int lt = (blockIdx.x >> 1) & 127; int b = blockIdx.x >> 8;
  int l0 = lt << 5;
  __shared__ float sv[32][193];
  __shared__ float wt[192*48];
  __shared__ float sg[192], sb2[192];
  __shared__ float smu[32], srs[32];
  int tid = threadIdx.x;
  for (int idx = tid; idx < 6144; idx += 256){ int r = idx/192, c = idx - r*192;
    sv[r][c] = yf[((size_t)b*4096 + l0 + r)*192 + c]; }
  if (tid < 192){ sg[tid] = g[tid]; sb2[tid] = bta[tid]; }
  int o0 = og*48;
  for (int idx = tid; idx < 9216; idx += 256){ int o = idx % 48, c = idx/48;
    wt[c*48 + o] = opw[(size_t)(o0 + o)*192 + c]; }
  __syncthreads();
  if (tid < 32){
    float s1 = 0.f, s2 = 0.f;
    for (int c = 0; c < 192; c++){ float v = sv[tid][c]; s1 += v; s2 += v*v; }
    float mu = s1*(1.0f/192.0f);
    smu[tid] = mu; srs[tid] = rsqrtf(s2*(1.0f/192.0f) - mu*mu + 1e-5f);
  }
  __syncthreads();
  for (int idx = tid; idx < 6144; idx += 256){ int l = idx & 31, c = idx >> 5;
    float zv = zT[((size_t)b*192 + c)*4096 + l0 + l];
    float v = sv[l][c];
    float yn = (v - smu[l])*srs[l]*sg[c] + sb2[c];
    sv[l][c] = yn * (zv/(1.f + __expf(-zv)));
  }
  __syncthreads();
  int l = tid & 31, grp = tid >> 5;
  float acc[6];
  #pragma unroll
  for (int j = 0; j < 6; j++) acc[j] = 0.f;
  for (int c = 0; c < 192; c++){
    float svv = sv[l][c];
    const float* wr = &wt[c*48 + grp*6];
    #pragma unroll
    for (int j = 0; j < 6; j += 2){
      float2 w2 = *(const float2*)&wr[j];
      acc[j]   += svv*w2.x; acc[j+1] += svv*w2.y;
    }
  }
  size_t ob = ((size_t)b*4096 + l0 + l)*96 + o0 + grp*6;
  #pragma unroll
  for (int j = 0; j < 6; j++) acc[j] += x[ob + j];
  #pragma unroll
  for (int j = 0; j < 6; j += 2){
    float2 v2; v2.x = acc[j]; v2.y = acc[j+1];
    *(float2*)&out[ob + j] = v2;
  }
}

// ================================================================ host
extern "C" void kernel_launch(void* const* d_in, const int* in_sizes, int n_in,
                              void* d_out, int out_size, void* d_ws, size_t ws_size,
                              hipStream_t stream){
  (void)in_sizes; (void)n_in; (void)out_size;
  const float* ix   = (const float*)d_in[0];
  const float* ipw  = (const float*)d_in[1];
  const float* fw1  = (const float*)d_in[2];
  const float* fb1  = (const float*)d_in[3];
  const float* fw2  = (const float*)d_in[4];
  const float* fb2  = (const float*)d_in[5];
  const float* ww   = (const float*)d_in[6];
  const float* wb   = (const float*)d_in[7];
  const float* dww  = (const float*)d_in[8];
  const float* dwb  = (const float*)d_in[9];
  const float* symw = (const float*)d_in[10];
  const float* xpw  = (const float*)d_in[11];
  const float* dtw  = (const float*)d_in[12];
  const float* dtb  = (const float*)d_in[13];
  const float* alog = (const float*)d_in[14];
  const float* Dsp  = (const float*)d_in[15];
  const float* ong  = (const float*)d_in[16];
  const float* onb  = (const float*)d_in[17];
  const float* opw  = (const float*)d_in[18];
  const float* rmsw = (const float*)d_in[19];

  float* W = (float*)d_ws;
  const size_t SZ_BLC = 3145728, SZ_F = 1622016, SZ_H = 786432;
  float* zT  = W;
  float* ab  = zT + SZ_BLC;
  float* R0  = ab + SZ_BLC;
  // phase 1
  float* xc    = R0;
  float* fre   = xc  + SZ_BLC;
  float* fim   = fre + SZ_F;
  float* fab   = fim + SZ_F;
  float* mb    = fab + SZ_F;
  float* llb   = mb  + SZ_F;
  float* lhb   = llb + SZ_H;
  float* wpart = lhb + 3*SZ_H;
  // phase 2
  float* Bsb  = R0;
  float* Csb  = Bsb + 1048576;
  float* dlsb = Csb + 1048576;
  float* xsb  = dlsb + 393216;
  float* Pb   = xsb + 12582912;
  float* aT   = Pb;
  float* Qb   = Pb + SZ_BLC;
  float* Yb   = Qb;
  float* ybA  = Qb + SZ_BLC;
  float* yfb  = xsb;

  const size_t NEED_BIG = (size_t)(6291456 + 30801920) * 4;
  bool bigws = (ws_size >= NEED_BIG);

  hipLaunchKernelGGL(k_rms_inproj, dim3(2048),   dim3(256), 0, stream, ix, rmsw, ipw, xc, zT);
  hipLaunchKernelGGL(k_dft_fwd,    dim3(4*192),  dim3(256), 0, stream, xc, fre, fim, fab,
                     llb, lhb, lhb + SZ_H, lhb + 2*SZ_H);
  hipLaunchKernelGGL(k_cmix1,      dim3(864),    dim3(256), 0, stream, fab, fw1, fb1, mb);
  hipLaunchKernelGGL(k_cmix2,      dim3(864),    dim3(256), 0, stream, mb, fw2, fb2, fre, fim, fab);
  hipLaunchKernelGGL(k_wconv,      dim3(864),    dim3(256), 0, stream, lhb, ww, wpart);
  hipLaunchKernelGGL(k_ifwd,       dim3(768),    dim3(256), 0, stream, fre, fim, xc, llb, wpart, wb, dww, dwb, ab, aT);
  hipLaunchKernelGGL(k_xproj,      dim3(1024),   dim3(256), 0, stream, ab, aT, xpw, Bsb, Csb, dlsb, xsb);
  hipLaunchKernelGGL(k_scanA,      dim3(1024),   dim3(192), 0, stream, xsb, dlsb, Bsb, dtw, dtb, alog, Pb, Qb);
  hipLaunchKernelGGL(k_scanB,      dim3(192),    dim3(256), 0, stream, Pb, Qb);
  if (bigws){
    hipLaunchKernelGGL(k_scanC_buf,  dim3(1024), dim3(192), 0, stream, xsb, dlsb, Bsb, Csb, Pb, dtw, dtb, alog, Dsp, Yb);
    hipLaunchKernelGGL(k_final_comb, dim3(1024), dim3(256), 0, stream, Yb, symw, zT, ong, onb, opw, ix, (float*)d_out);
  } else {
    hipLaunchKernelGGL(k_zero,       dim3(12288), dim3(256), 0, stream, ybA, (int)SZ_BLC);
    hipLaunchKernelGGL(k_scanC_atom, dim3(1024),  dim3(192), 0, stream, xsb, dlsb, Bsb, Csb, Pb, dtw, dtb, alog, Dsp, ybA);
    hipLaunchKernelGGL(k_enh,        dim3(12288), dim3(256), 0, stream, ybA, symw, yfb);
    hipLaunchKernelGGL(k_final,      dim3(1024),  dim3(256), 0, stream, yfb, zT, ong, onb, opw, ix, (float*)d_out);
  }
}

// Round 12
// 817.959 us; speedup vs baseline: 1.0169x; 1.0169x over previous
//
#include <hip/hip_runtime.h>
#include <hip/hip_bf16.h>

#define CI 192
#define LL_ 4096

typedef __bf16 v8bf __attribute__((ext_vector_type(8)));
typedef float  v4f  __attribute__((ext_vector_type(4)));
typedef unsigned short v8us __attribute__((ext_vector_type(8)));

__device__ __forceinline__ unsigned short f2bf(float v){
  unsigned int u = __float_as_uint(v);
  return (unsigned short)((u + 0x7FFFu + ((u >> 16) & 1u)) >> 16);
}

__global__ __launch_bounds__(256) void k_zero(float* __restrict__ p, int n){
  int i = blockIdx.x*256 + threadIdx.x;
  if (i < n) p[i] = 0.f;
}

// ------------------------------------------------ K1: RMSNorm + in_proj (tiled GEMM, 48-o tiles)
__global__ __launch_bounds__(256) void k_rms_inproj(const float* __restrict__ x,
    const float* __restrict__ rmsw, const float* __restrict__ ipw,
    float* __restrict__ xc, float* __restrict__ zT){
  int og = blockIdx.x & 7; int lt = (blockIdx.x >> 3) & 63; int b = blockIdx.x >> 9;
  int l0 = lt << 6;
  __shared__ float xt[64][97];
  __shared__ float wt[96*48];
  __shared__ float rr[64];
  __shared__ float rw[96];
  int tid = threadIdx.x;
  for (int idx = tid; idx < 6144; idx += 256){ int r = idx/96, d = idx - r*96;
    xt[r][d] = x[((size_t)b*4096 + l0 + r)*96 + d]; }
  if (tid < 96) rw[tid] = rmsw[tid];
  int o0 = og*48;
  for (int idx = tid; idx < 4608; idx += 256){ int o = idx%48, d = idx/48;
    wt[d*48 + o] = ipw[(size_t)(o0 + o)*96 + d]; }
  __syncthreads();
  if (tid < 64){
    float s = 0.f;
    for (int d = 0; d < 96; d++){ float v = xt[tid][d]; s += v*v; }
    rr[tid] = rsqrtf(s*(1.0f/96.0f) + 1e-5f);
  }
  __syncthreads();
  for (int idx = tid; idx < 6144; idx += 256){ int r = idx/96, d = idx - r*96;
    xt[r][d] *= rr[r]*rw[d]; }
  __syncthreads();
  int l = tid & 63, grp = tid >> 6;
  float acc[12];
  #pragma unroll
  for (int j = 0; j < 12; j++) acc[j] = 0.f;
  for (int d = 0; d < 96; d++){
    float xv = xt[l][d];
    const float* wr = &wt[d*48 + grp*12];
    #pragma unroll
    for (int j = 0; j < 12; j += 4){
      float4 w4 = *(const float4*)&wr[j];
      acc[j]   += xv*w4.x; acc[j+1] += xv*w4.y;
      acc[j+2] += xv*w4.z; acc[j+3] += xv*w4.w;
    }
  }
  #pragma unroll
  for (int j = 0; j < 12; j++){
    int o = o0 + grp*12 + j;
    if (o < 192) xc[((size_t)b*192 + o)*4096 + l0 + l] = acc[j];
    else         zT[((size_t)b*192 + (o-192))*4096 + l0 + l] = acc[j];
  }
}

// ------------------------------------------------ K2: forward rfft2 (ortho) + fused Haar DWT
__global__ __launch_bounds__(256) void k_dft_fwd(const float* __restrict__ xc,
    float* __restrict__ fre, float* __restrict__ fim, float* __restrict__ fab,
    float* __restrict__ ll, float* __restrict__ lh, float* __restrict__ hl, float* __restrict__ hh){
  int plane = blockIdx.x;
  __shared__ float sxT[64*65];
  __shared__ float t1r[64*34], t1i[64*34];
  __shared__ float tabr[16], tabi[16];
  __shared__ float ct64[64], st64[64];
  int tid = threadIdx.x;
  const float* X = xc + (size_t)plane*4096;
  for (int i = tid; i < 4096; i += 256){ int h = i >> 6, w = i & 63; sxT[w*65 + h] = X[i]; }
  if (tid < 16){ tabr[tid] = cospif((float)tid/8.0f); tabi[tid] = -sinpif((float)tid/8.0f); }
  if (tid < 64){ ct64[tid] = cospif((float)tid/32.0f); st64[tid] = sinpif((float)tid/32.0f); }
  __syncthreads();
  {
    size_t qbase = (size_t)plane*1024;
    for (int idx = tid; idx < 1024; idx += 256){
      int y2 = idx >> 5, x2 = idx & 31;
      float a_ = sxT[(2*x2)*65 + 2*y2],     b_ = sxT[(2*x2+1)*65 + 2*y2];
      float c_ = sxT[(2*x2)*65 + 2*y2+1],   d_ = sxT[(2*x2+1)*65 + 2*y2+1];
      ll[qbase + idx] = (a_+b_+c_+d_)*0.5f; lh[qbase + idx] = (a_-b_+c_-d_)*0.5f;
      hl[qbase + idx] = (a_+b_-c_-d_)*0.5f; hh[qbase + idx] = (a_-b_-c_+d_)*0.5f;
    }
  }
  {
    int hp = tid & 31, g = tid >> 5;
    float a0r[4], a0i[4], a1r[4], a1i[4];
    #pragma unroll
    for (int j = 0; j < 4; j++){ a0r[j]=0.f; a0i[j]=0.f; a1r[j]=0.f; a1i[j]=0.f; }
    float s32_0 = 0.f, s32_1 = 0.f;
    for (int w = 0; w < 64; w++){
      float xv0 = sxT[w*65 + hp];
      float xv1 = sxT[w*65 + hp + 32];
      int m0 = (w*g) & 15;
      float twr = tabr[m0], twi = tabi[m0];
      int ms = w & 15;
      float str = tabr[ms], sti = tabi[ms];
      #pragma unroll
      for (int j = 0; j < 4; j++){
        a0r[j] += xv0*twr; a0i[j] += xv0*twi;
        a1r[j] += xv1*twr; a1i[j] += xv1*twi;
        float nr = twr*str - twi*sti;
        float ni = twr*sti + twi*str;
        twr = nr; twi = ni;
      }
      if (g == 0){ float sg = (w & 1) ? -1.f : 1.f; s32_0 += xv0*sg; s32_1 += xv1*sg; }
    }
    #pragma unroll
    for (int j = 0; j < 4; j++){
      int k = 4*g + j;
      t1r[hp*34 + k] = a0r[j];        t1i[hp*34 + k] = a0i[j];
      t1r[(hp+32)*34 + k] = a1r[j];   t1i[(hp+32)*34 + k] = a1i[j];
    }
    if (g == 0){
      t1r[hp*34 + 32] = s32_0;      t1i[hp*34 + 32] = 0.f;
      t1r[(hp+32)*34 + 32] = s32_1; t1i[(hp+32)*34 + 32] = 0.f;
    }
  }
  __syncthreads();
  {
    int fp = tid & 31, g = tid >> 5;
    float stepr = cospif((float)fp/32.0f), stepi = -sinpif((float)fp/32.0f);
    float a0r[4], a0i[4], a1r[4], a1i[4];
    #pragma unroll
    for (int j = 0; j < 4; j++){ a0r[j]=0.f; a0i[j]=0.f; a1r[j]=0.f; a1i[j]=0.f; }
    float b0r=0.f, b0i=0.f, b1r=0.f, b1i=0.f;
    for (int hb = 0; hb < 4; hb++){
      int m = ((hb*16)*fp) & 63;
      float twr = ct64[m], twi = -st64[m];
      for (int hh2 = 0; hh2 < 16; hh2++){
        int h = hb*16 + hh2;
        float sg = (h & 1) ? -1.f : 1.f;
        #pragma unroll
        for (int j = 0; j < 4; j++){
          float Tr = t1r[h*34 + 4*g + j], Ti = t1i[h*34 + 4*g + j];
          float pr = Tr*twr - Ti*twi;
          float pi = Tr*twi + Ti*twr;
          a0r[j] += pr; a0i[j] += pi;
          a1r[j] += sg*pr; a1i[j] += sg*pi;
        }
        if (g == 0){
          float Tr = t1r[h*34 + 32], Ti = t1i[h*34 + 32];
          float pr = Tr*twr - Ti*twi, pi = Tr*twi + Ti*twr;
          b0r += pr; b0i += pi; b1r += sg*pr; b1i += sg*pi;
        }
        float nr = twr*stepr - twi*stepi, ni = twr*stepi + twi*stepr;
        twr = nr; twi = ni;
      }
    }
    size_t base = (size_t)plane*2112;
    #pragma unroll
    for (int j = 0; j < 4; j++){
      int k = 4*g + j;
      float r0 = a0r[j]*(1.f/64.f), i0 = a0i[j]*(1.f/64.f);
      float r1 = a1r[j]*(1.f/64.f), i1 = a1i[j]*(1.f/64.f);
      fre[base + fp*33 + k] = r0; fim[base + fp*33 + k] = i0;
      fab[base + fp*33 + k] = sqrtf(r0*r0 + i0*i0);
      fre[base + (fp+32)*33 + k] = r1; fim[base + (fp+32)*33 + k] = i1;
      fab[base + (fp+32)*33 + k] = sqrtf(r1*r1 + i1*i1);
    }
    if (g == 0){
      float r0 = b0r*(1.f/64.f), i0 = b0i*(1.f/64.f);
      float r1 = b1r*(1.f/64.f), i1 = b1i*(1.f/64.f);
      fre[base + fp*33 + 32] = r0; fim[base + fp*33 + 32] = i0;
      fab[base + fp*33 + 32] = sqrtf(r0*r0 + i0*i0);
      fre[base + (fp+32)*33 + 32] = r1; fim[base + (fp+32)*33 + 32] = i1;
      fab[base + (fp+32)*33 + 32] = sqrtf(r1*r1 + i1*i1);
    }
  }
}

// ------------------------------------------------ K3: m = gelu(W1 @ |xf| + b1)  (LDS weights)
__global__ __launch_bounds__(256) void k_cmix1(const float* __restrict__ fab,
    const float* __restrict__ w1, const float* __restrict__ b1, float* __restrict__ m){
  int bid = blockIdx.x;
  int pt = bid % 9; int og = (bid/9) % 24; int b = bid/216;
  int tid = threadIdx.x;
  int p = pt*256 + tid; bool act = p < 2112;
  __shared__ float wl[192*8];
  for (int idx = tid; idx < 1536; idx += 256){ int o = idx & 7, c = idx >> 3;
    wl[c*8 + o] = w1[(size_t)(og*8 + o)*192 + c]; }
  __syncthreads();
  float acc[8];
  #pragma unroll
  for (int o = 0; o < 8; o++) acc[o] = b1[og*8 + o];
  const float* xb = fab + (size_t)b*CI*2112 + p;
  for (int c = 0; c < 192; c++){
    float xv = act ? xb[(size_t)c*2112] : 0.f;
    float4 wa = *(const float4*)&wl[c*8];
    float4 wb4 = *(const float4*)&wl[c*8 + 4];
    acc[0] += xv*wa.x;  acc[1] += xv*wa.y;  acc[2] += xv*wa.z;  acc[3] += xv*wa.w;
    acc[4] += xv*wb4.x; acc[5] += xv*wb4.y; acc[6] += xv*wb4.z; acc[7] += xv*wb4.w;
  }
  if (act){
    #pragma unroll
    for (int o = 0; o < 8; o++){
      float a = acc[o];
      m[((size_t)b*192 + og*8 + o)*2112 + p] = 0.5f*a*(1.0f + erff(a*0.70710678118654752f));
    }
  }
}

// ------------------------------------------------ K4: mag = W2 @ m + b2; in-place (LDS weights)
__global__ __launch_bounds__(256) void k_cmix2(const float* __restrict__ m,
    const float* __restrict__ w2, const float* __restrict__ bi2,
    float* __restrict__ fre, float* __restrict__ fim, const float* __restrict__ fab){
  int bid = blockIdx.x;
  int pt = bid % 9; int og = (bid/9) % 24; int b = bid/216;
  int tid = threadIdx.x;
  int p = pt*256 + tid; bool act = p < 2112;
  __shared__ float wl[192*8];
  for (int idx = tid; idx < 1536; idx += 256){ int o = idx & 7, c = idx >> 3;
    wl[c*8 + o] = w2[(size_t)(og*8 + o)*192 + c]; }
  __syncthreads();
  float acc[8];
  #pragma unroll
  for (int o = 0; o < 8; o++) acc[o] = bi2[og*8 + o];
  const float* xb = m + (size_t)b*CI*2112 + p;
  for (int c = 0; c < 192; c++){
    float xv = act ? xb[(size_t)c*2112] : 0.f;
    float4 wa = *(const float4*)&wl[c*8];
    float4 wb4 = *(const float4*)&wl[c*8 + 4];
    acc[0] += xv*wa.x;  acc[1] += xv*wa.y;  acc[2] += xv*wa.z;  acc[3] += xv*wa.w;
    acc[4] += xv*wb4.x; acc[5] += xv*wb4.y; acc[6] += xv*wb4.z; acc[7] += xv*wb4.w;
  }
  if (act){
    #pragma unroll
    for (int o = 0; o < 8; o++){
      size_t id = ((size_t)b*192 + og*8 + o)*2112 + p;
      float ab = fab[id];
      float re, im;
      if (ab > 1e-30f){ float sc = acc[o]/ab; re = sc*fre[id]; im = sc*fim[id]; }
      else { re = acc[o]; im = 0.f; }
      fre[id] = re; fim[id] = im;
    }
  }
}

// ------------------------------------------------ K5a: convert DWT bands -> padded bf16, ic-fastest
// pb2[img(12)][34*34][192ic]  (img = t*4+b)
__global__ __launch_bounds__(256) void k_cvt_in(const float* __restrict__ lhb,
    unsigned short* __restrict__ pb2, int total){
  int idx = blockIdx.x*256 + threadIdx.x;
  if (idx >= total) return;
  int ic = idx % 192; int rest = idx / 192;
  int r = rest % 1156; int img = rest / 1156;
  int y = r / 34, xq = r - y*34;
  int yg = y - 1, xg = xq - 1;
  float v = (yg >= 0 && yg < 32 && xg >= 0 && xg < 32)
            ? lhb[((size_t)img*192 + ic)*1024 + yg*32 + xg] : 0.f;
  pb2[idx] = f2bf(v);
}

// ------------------------------------------------ K5b: convert weights -> bf16 [q][oc][ic]
__global__ __launch_bounds__(256) void k_cvt_w(const float* __restrict__ ww,
    unsigned short* __restrict__ wqb2){
  int idx = blockIdx.x*256 + threadIdx.x;
  if (idx >= 331776) return;
  int ic = idx % 192; int rest = idx / 192;
  int oc = rest % 192; int q = rest / 192;
  wqb2[idx] = f2bf(ww[((size_t)oc*192 + ic)*9 + q]);
}

// ------------------------------------------------ K6: 3x3 full conv via bf16 MFMA
// grid 576: nt(3: 64 oc) x mt(16: 64 spatial) x img(12, slowest -> XCD locality)
__global__ __launch_bounds__(256) void k_wconv_mfma(const unsigned short* __restrict__ pb2,
    const unsigned short* __restrict__ wqb2, float* __restrict__ wnew){
  int bid = blockIdx.x;
  int nt = bid % 3; int mt = (bid/3) & 15; int img = bid/48;
  int o0 = nt*64;
  __shared__ __align__(16) float smemf[4160];       // 16.6 KB; Abuf/Bbuf alias head
  unsigned short* Abuf = (unsigned short*)smemf;          // [64 m][40] (32 ic used)
  unsigned short* Bbuf = Abuf + 2560;                     // [64 oc][40]
  float* T = smemf;                                        // epilogue [64 m][65]
  int tid = threadIdx.x;
  int lane = tid & 63, wv = tid >> 6;
  int quad = lane >> 4, n16 = lane & 15;
  v4f acc[4];
  #pragma unroll
  for (int t2 = 0; t2 < 4; t2++) acc[t2] = (v4f){0.f,0.f,0.f,0.f};
  const unsigned short* pimg = pb2 + (size_t)img*1156*192;
  for (int q = 0; q < 9; q++){
    int ky = q/3, kx = q - ky*3;
    for (int icc = 0; icc < 6; icc++){
      int c0 = icc*32;
      // stage A [64 m][32 ic]: global ic-fastest (coalesced)
      for (int idx = tid; idx < 2048; idx += 256){
        int ic = idx & 31, mm = idx >> 5;
        int off = (2*mt + (mm >> 5) + ky)*34 + (mm & 31) + kx;
        Abuf[mm*40 + ic] = pimg[(size_t)off*192 + c0 + ic];
      }
      // stage B [64 oc][32 ic]
      for (int idx = tid; idx < 2048; idx += 256){
        int ic = idx & 31, oc = idx >> 5;
        Bbuf[oc*40 + ic] = wqb2[((size_t)(q*192) + o0 + oc)*192 + c0 + ic];
      }
      __syncthreads();
      v8us bu = *(const v8us*)&Bbuf[(16*wv + n16)*40 + quad*8];
      v8bf bv = __builtin_bit_cast(v8bf, bu);
      #pragma unroll
      for (int t2 = 0; t2 < 4; t2++){
        v8us au = *(const v8us*)&Abuf[(16*t2 + n16)*40 + quad*8];
        v8bf av = __builtin_bit_cast(v8bf, au);
        acc[t2] = __builtin_amdgcn_mfma_f32_16x16x32_bf16(av, bv, acc[t2], 0, 0, 0);
      }
      __syncthreads();
    }
  }
  // epilogue: regs -> T[64 m][65] -> coalesced store (wnew[img][oc][1024])
  #pragma unroll
  for (int t2 = 0; t2 < 4; t2++)
    #pragma unroll
    for (int r = 0; r < 4; r++)
      T[(16*t2 + quad*4 + r)*65 + 16*wv + n16] = acc[t2][r];
  __syncthreads();
  float* outb = wnew + (size_t)img*196608;
  for (int idx = tid; idx < 4096; idx += 256){
    int mm = idx & 63, oc = idx >> 6;
    outb[(size_t)(o0 + oc)*1024 + mt*64 + mm] = T[mm*65 + oc];
  }
}

// ------------------------------------------------ K7 (fused): irfft2 + combine + depthwise3x3 + SiLU -> ab, aT
__global__ __launch_bounds__(256) void k_ifwd(const float* __restrict__ fre2,
    const float* __restrict__ fim2, const float* __restrict__ xc,
    const float* __restrict__ ll, const float* __restrict__ wnew, const float* __restrict__ wb,
    const float* __restrict__ dww, const float* __restrict__ dwb,
    float* __restrict__ ab, float* __restrict__ aT){
  int plane = blockIdx.x;
  int c = plane % 192;
  __shared__ float sm[12936];
  float* gr  = sm;
  float* gi  = sm + 2176;
  float* ur  = sm + 4352;
  float* ui  = sm + 6528;
  float* sx2 = sm + 8704;
  float* t64r = sm + 12800; float* t64i = sm + 12864;
  float* t4r  = sm + 12928; float* t4i  = sm + 12932;
  float* scratch = sm;
  int tid = threadIdx.x;
  for (int i = tid; i < 2112; i += 256){
    size_t o = (size_t)plane*2112 + i;
    int f = i/33, k = i - f*33;
    gr[f*34 + k] = fre2[o]; gi[f*34 + k] = fim2[o];
  }
  if (tid < 64){ t64r[tid] = cospif((float)tid/32.0f); t64i[tid] = sinpif((float)tid/32.0f); }
  if (tid < 4){ t4r[tid] = (tid == 0) ? 1.f : ((tid == 2) ? -1.f : 0.f);
                t4i[tid] = (tid == 1) ? 1.f : ((tid == 3) ? -1.f : 0.f); }
  __syncthreads();
  {
    int hp = tid & 31, g = tid >> 5;
    float stepr = cospif((float)hp/32.0f), stepi = sinpif((float)hp/32.0f);
    float a0r[4], a0i[4], a1r[4], a1i[4];
    #pragma unroll
    for (int j = 0; j < 4; j++){ a0r[j]=0.f; a0i[j]=0.f; a1r[j]=0.f; a1i[j]=0.f; }
    float b0r=0.f, b0i=0.f, b1r=0.f, b1i=0.f;
    for (int fb = 0; fb < 4; fb++){
      int m = ((fb*16)*hp) & 63;
      float twr = t64r[m], twi = t64i[m];
      for (int ff = 0; ff < 16; ff++){
        int f = fb*16 + ff;
        float sg = (f & 1) ? -1.f : 1.f;
        #pragma unroll
        for (int j = 0; j < 4; j++){
          float Gr = gr[f*34 + 4*g + j], Gi = gi[f*34 + 4*g + j];
          float pr = Gr*twr - Gi*twi;
          float pi = Gr*twi + Gi*twr;
          a0r[j] += pr; a0i[j] += pi;
          a1r[j] += sg*pr; a1i[j] += sg*pi;
        }
        if (g == 0){
          float Gr = gr[f*34 + 32], Gi = gi[f*34 + 32];
          float pr = Gr*twr - Gi*twi, pi = Gr*twi + Gi*twr;
          b0r += pr; b0i += pi; b1r += sg*pr; b1i += sg*pi;
        }
        float nr = twr*stepr - twi*stepi, ni = twr*stepi + twi*stepr;
        twr = nr; twi = ni;
      }
    }
    __syncthreads();
    #pragma unroll
    for (int j = 0; j < 4; j++){
      int k = 4*g + j;
      float ck = (k == 0) ? (1.f/64.f) : (2.f/64.f);
      ur[hp*34 + k] = a0r[j]*ck;       ui[hp*34 + k] = a0i[j]*ck;
      ur[(hp+32)*34 + k] = a1r[j]*ck;  ui[(hp+32)*34 + k] = a1i[j]*ck;
    }
    if (g == 0){
      ur[hp*34 + 32] = b0r*(1.f/64.f);      ui[hp*34 + 32] = b0i*(1.f/64.f);
      ur[(hp+32)*34 + 32] = b1r*(1.f/64.f); ui[(hp+32)*34 + 32] = b1i*(1.f/64.f);
    }
  }
  __syncthreads();
  {
    int h = tid & 63, wg = tid >> 6;
    float acc[16];
    #pragma unroll
    for (int j = 0; j < 16; j++) acc[j] = 0.f;
    for (int k = 0; k <= 32; k++){
      float Ur = ur[h*34 + k], Ui = ui[h*34 + k];
      int m = (k*wg) & 3;
      float twr = t4r[m], twi = t4i[m];
      float str = t64r[k], sti = t64i[k];
      #pragma unroll
      for (int j = 0; j < 16; j++){
        acc[j] += Ur*twr - Ui*twi;
        float nr = twr*str - twi*sti, ni = twr*sti + twi*str;
        twr = nr; twi = ni;
      }
    }
    #pragma unroll
    for (int j = 0; j < 16; j++) sx2[h*64 + 16*wg + j] = acc[j];
  }
  __syncthreads();
  float bia = wb[c];
  for (int p = tid; p < 4096; p += 256){
    int h = p >> 6, w = p & 63;
    size_t q = (size_t)plane*1024 + (size_t)(h >> 1)*32 + (w >> 1);
    float LLv = ll[q];
    float LH = wnew[q] + bia;
    float HL = wnew[786432 + q] + bia;
    float HH = wnew[1572864 + q] + bia;
    float v;
    bool hb = (h & 1), wbit = (w & 1);
    if (!hb && !wbit)      v = (LLv + LH + HL + HH)*0.5f;
    else if (!hb && wbit)  v = (LLv - LH + HL - HH)*0.5f;
    else if (hb && !wbit)  v = (LLv + LH - HL - HH)*0.5f;
    else                   v = (LLv - LH - HL + HH)*0.5f;
    sx2[p] = 2.0f*xc[(size_t)plane*4096 + p] + sx2[p] + v;
  }
  __syncthreads();
  float wk[9];
  #pragma unroll
  for (int q = 0; q < 9; q++) wk[q] = dww[c*9 + q];
  float dbv = dwb[c];
  for (int p = tid; p < 4096; p += 256){
    int h = p >> 6, w = p & 63;
    float acc = dbv;
    #pragma unroll
    for (int ky = 0; ky < 3; ky++){
      int yy = h + ky - 1; if (yy < 0 || yy > 63) continue;
      #pragma unroll
      for (int kx = 0; kx < 3; kx++){
        int xx = w + kx - 1; if (xx < 0 || xx > 63) continue;
        acc += sx2[yy*64 + xx]*wk[ky*3 + kx];
      }
    }
    scratch[h*65 + w] = acc / (1.f + __expf(-acc));
  }
  __syncthreads();
  float* abp = ab + (size_t)plane*4096;
  float* aTp = aT + (size_t)plane*4096;
  for (int p = tid; p < 4096; p += 256){
    abp[p] = scratch[(p >> 6)*65 + (p & 63)];
    aTp[p] = scratch[(p & 63)*65 + (p >> 6)];
  }
}

// ------------------------------------------------ K10: x_proj; wave-split GEMM
__global__ __launch_bounds__(256) void k_xproj(const float* __restrict__ ab,
    const float* __restrict__ aT, const float* __restrict__ xpw,
    float* __restrict__ Bsb, float* __restrict__ Csb, float* __restrict__ dlsb,
    float* __restrict__ xsb){
  int bid = blockIdx.x;
  int s = bid & 63; int k = (bid >> 6) & 3; int b = bid >> 8;
  int tid = threadIdx.x;
  __shared__ float als[192][65];
  __shared__ float dls[6][64];
  int l0 = s << 6;
  const float* src = (k & 1) ? aT : ab;
  int off0 = (k < 2) ? l0 : (4095 - l0);
  int stp  = (k < 2) ? 1 : -1;
  for (int idx = tid; idx < 192*64; idx += 256){
    int d = idx >> 6, i = idx & 63;
    als[d][i] = src[((size_t)b*192 + d)*4096 + off0 + stp*i];
  }
  __syncthreads();
  {
    int i = tid & 63, wg = tid >> 6;
    const float* wr[10];
    #pragma unroll
    for (int r = 0; r < 10; r++){
      int cp = wg + 4*r; if (cp > 37) cp = 37;
      wr[r] = xpw + ((size_t)k*38 + cp)*192;
    }
    float acc[10];
    #pragma unroll
    for (int r = 0; r < 10; r++) acc[r] = 0.f;
    for (int d = 0; d < 192; d++){
      float v = als[d][i];
      #pragma unroll
      for (int r = 0; r < 10; r++) acc[r] += v*wr[r][d];
    }
    #pragma unroll
    for (int r = 0; r < 10; r++){
      int cp = wg + 4*r;
      if (cp > 37) continue;
      if (cp < 6) dls[cp][i] = acc[r];
      else if (cp < 22) Bsb[((size_t)(b*4 + k)*16 + (cp - 6 ))*4096 + l0 + i] = acc[r];
      else              Csb[((size_t)(b*4 + k)*16 + (cp - 22))*4096 + l0 + i] = acc[r];
    }
  }
  size_t xbase = ((size_t)(b*4 + k)*4096 + l0)*192;
  for (int j = tid; j < 192*64; j += 256){
    int i = j / 192, c = j % 192;
    xsb[xbase + (size_t)i*192 + c] = als[c][i];
  }
  __syncthreads();
  size_t dbase = (size_t)((b*4 + k)*64 + s)*384;
  for (int j = tid; j < 384; j += 256){
    int i = j/6, r = j - i*6;
    dlsb[dbase + j] = dls[r][i];
  }
}

// ------------------------------------------------ K11: scan phase A (fast-exp)
__global__ __launch_bounds__(192) void k_scanA(const float* __restrict__ xsb,
    const float* __restrict__ dlsb, const float* __restrict__ Bsb,
    const float* __restrict__ dtw, const float* __restrict__ dtb,
    const float* __restrict__ alog, float* __restrict__ Pb, float* __restrict__ Qb){
  int bid = blockIdx.x; int s = bid & 63; int k = (bid >> 6) & 3; int b = bid >> 8;
  int c = threadIdx.x; int bk = b*4 + k;
  __shared__ float sdl[384];
  __shared__ float sB[16][64];
  size_t dbase = (size_t)(bk*64 + s)*384;
  for (int j = c; j < 384; j += 192) sdl[j] = dlsb[dbase + j];
  for (int j = c; j < 1024; j += 192){ int n = j >> 6, i = j & 63;
    sB[n][i] = Bsb[((size_t)bk*16 + n)*4096 + (s << 6) + i]; }
  __syncthreads();
  float A[16], P[16], Q[16];
  const float* arow = alog + ((size_t)k*192 + c)*16;
  bool fast = true;
  #pragma unroll
  for (int n = 0; n < 16; n++){
    A[n] = -__expf(arow[n]); P[n] = 1.f; Q[n] = 0.f;
    if (fabsf(A[n] + (float)(n+1)) > 1e-3f) fast = false;
  }
  float dw[6];
  #pragma unroll
  for (int r = 0; r < 6; r++) dw[r] = dtw[((size_t)k*192 + c)*6 + r];
  float db = dtb[k*192 + c];
  const float* xrow = xsb + ((size_t)bk*4096 + (s << 6))*192 + c;
  if (fast){
    for (int i = 0; i < 64; i++){
      float u = xrow[(size_t)i*192];
      float acc = db;
      #pragma unroll
      for (int r = 0; r < 6; r++) acc += sdl[i*6 + r]*dw[r];
      float dl = fmaxf(acc, 0.f) + log1pf(__expf(-fabsf(acc)));
      float du = dl*u;
      float e1 = __expf(-dl), e = 1.f;
      #pragma unroll
      for (int n = 0; n < 16; n++){
        e *= e1;
        P[n] *= e;
        Q[n] = Q[n]*e + du*sB[n][i];
      }
    }
  } else {
    for (int i = 0; i < 64; i++){
      float u = xrow[(size_t)i*192];
      float acc = db;
      #pragma unroll
      for (int r = 0; r < 6; r++) acc += sdl[i*6 + r]*dw[r];
      float dl = fmaxf(acc, 0.f) + log1pf(__expf(-fabsf(acc)));
      float du = dl*u;
      #pragma unroll
      for (int n = 0; n < 16; n++){
        float e = __expf(dl*A[n]);
        P[n] *= e;
        Q[n] = Q[n]*e + du*sB[n][i];
      }
    }
  }
  size_t pbase = ((size_t)(bk*64 + s)*16)*192 + c;
  #pragma unroll
  for (int n = 0; n < 16; n++){ Pb[pbase + (size_t)n*192] = P[n]; Qb[pbase + (size_t)n*192] = Q[n]; }
}

// ------------------------------------------------ K12: scan phase B (hin in-place over Pb)
__global__ __launch_bounds__(256) void k_scanB(float* __restrict__ Pb,
    const float* __restrict__ Qb){
  int id = blockIdx.x*256 + threadIdx.x;
  int c = id % 192; int rest = id / 192; int n = rest % 16; int bk = rest / 16;
  float h = 0.f;
  for (int s = 0; s < 64; s++){
    size_t o = (((size_t)bk*64 + s)*16 + n)*192 + c;
    float P = Pb[o], Q = Qb[o];
    Pb[o] = h;
    h = P*h + Q;
  }
}

// ------------------------------------------------ K13a: scan phase C — non-atomic (fast-exp)
__global__ __launch_bounds__(192) void k_scanC_buf(const float* __restrict__ xsb,
    const float* __restrict__ dlsb, const float* __restrict__ Bsb, const float* __restrict__ Csb,
    const float* __restrict__ hinb, const float* __restrict__ dtw, const float* __restrict__ dtb,
    const float* __restrict__ alog, const float* __restrict__ Dsp, float* __restrict__ Y){
  int bid = blockIdx.x; int s = bid & 63; int k = (bid >> 6) & 3; int b = bid >> 8;
  int c = threadIdx.x; int bk = b*4 + k;
  __shared__ float sdl[384];
  __shared__ float sB[16][64];
  __shared__ float sC[16][64];
  size_t dbase = (size_t)(bk*64 + s)*384;
  for (int j = c; j < 384; j += 192) sdl[j] = dlsb[dbase + j];
  for (int j = c; j < 1024; j += 192){ int n = j >> 6, i = j & 63;
    size_t o = ((size_t)bk*16 + n)*4096 + (s << 6) + i;
    sB[n][i] = Bsb[o]; sC[n][i] = Csb[o]; }
  __syncthreads();
  float A[16], h[16];
  const float* arow = alog + ((size_t)k*192 + c)*16;
  bool fast = true;
  #pragma unroll
  for (int n = 0; n < 16; n++){
    A[n] = -__expf(arow[n]);
    if (fabsf(A[n] + (float)(n+1)) > 1e-3f) fast = false;
  }
  size_t hbase = ((size_t)(bk*64 + s)*16)*192 + c;
  #pragma unroll
  for (int n = 0; n < 16; n++) h[n] = hinb[hbase + (size_t)n*192];
  float dw[6];
  #pragma unroll
  for (int r = 0; r < 6; r++) dw[r] = dtw[((size_t)k*192 + c)*6 + r];
  float db = dtb[k*192 + c];
  float Dc = Dsp[k*192 + c];
  const float* xrow = xsb + ((size_t)bk*4096 + (s << 6))*192 + c;
  int p0, pst;
  if (k == 0){ p0 = s << 6;        pst = 1;  }
  else if (k == 1){ p0 = s;        pst = 64; }
  else if (k == 2){ p0 = 4095 - (s << 6); pst = -1; }
  else { p0 = 4095 - s;            pst = -64; }
  float* Yk = Y + (((size_t)k*4 + b)*4096)*192;
  if (fast){
    for (int i = 0; i < 64; i++){
      float u = xrow[(size_t)i*192];
      float acc = db;
      #pragma unroll
      for (int r = 0; r < 6; r++) acc += sdl[i*6 + r]*dw[r];
      float dl = fmaxf(acc, 0.f) + log1pf(__expf(-fabsf(acc)));
      float du = dl*u;
      float e1 = __expf(-dl), e = 1.f;
      float y = 0.f;
      #pragma unroll
      for (int n = 0; n < 16; n++){
        e *= e1;
        h[n] = h[n]*e + du*sB[n][i];
        y += h[n]*sC[n][i];
      }
      Yk[(size_t)(p0 + pst*i)*192 + c] = y + u*Dc;
    }
  } else {
    for (int i = 0; i < 64; i++){
      float u = xrow[(size_t)i*192];
      float acc = db;
      #pragma unroll
      for (int r = 0; r < 6; r++) acc += sdl[i*6 + r]*dw[r];
      float dl = fmaxf(acc, 0.f) + log1pf(__expf(-fabsf(acc)));
      float du = dl*u;
      float y = 0.f;
      #pragma unroll
      for (int n = 0; n < 16; n++){
        float e = __expf(dl*A[n]);
        h[n] = h[n]*e + du*sB[n][i];
        y += h[n]*sC[n][i];
      }
      Yk[(size_t)(p0 + pst*i)*192 + c] = y + u*Dc;
    }
  }
}

// ------------------------------------------------ K13b: scan phase C — atomic fallback (fast-exp)
__global__ __launch_bounds__(192) void k_scanC_atom(const float* __restrict__ xsb,
    const float* __restrict__ dlsb, const float* __restrict__ Bsb, const float* __restrict__ Csb,
    const float* __restrict__ hinb, const float* __restrict__ dtw, const float* __restrict__ dtb,
    const float* __restrict__ alog, const float* __restrict__ Dsp, float* __restrict__ yb){
  int bid = blockIdx.x; int s = bid & 63; int k = (bid >> 6) & 3; int b = bid >> 8;
  int c = threadIdx.x; int bk = b*4 + k;
  __shared__ float sdl[384];
  __shared__ float sB[16][64];
  __shared__ float sC[16][64];
  size_t dbase = (size_t)(bk*64 + s)*384;
  for (int j = c; j < 384; j += 192) sdl[j] = dlsb[dbase + j];
  for (int j = c; j < 1024; j += 192){ int n = j >> 6, i = j & 63;
    size_t o = ((size_t)bk*16 + n)*4096 + (s << 6) + i;
    sB[n][i] = Bsb[o]; sC[n][i] = Csb[o]; }
  __syncthreads();
  float A[16], h[16];
  const float* arow = alog + ((size_t)k*192 + c)*16;
  bool fast = true;
  #pragma unroll
  for (int n = 0; n < 16; n++){
    A[n] = -__expf(arow[n]);
    if (fabsf(A[n] + (float)(n+1)) > 1e-3f) fast = false;
  }
  size_t hbase = ((size_t)(bk*64 + s)*16)*192 + c;
  #pragma unroll
  for (int n = 0; n < 16; n++) h[n] = hinb[hbase + (size_t)n*192];
  float dw[6];
  #pragma unroll
  for (int r = 0; r < 6; r++) dw[r] = dtw[((size_t)k*192 + c)*6 + r];
  float db = dtb[k*192 + c];
  float Dc = Dsp[k*192 + c];
  const float* xrow = xsb + ((size_t)bk*4096 + (s << 6))*192 + c;
  int p0, pst;
  if (k == 0){ p0 = s << 6;        pst = 1;  }
  else if (k == 1){ p0 = s;        pst = 64; }
  else if (k == 2){ p0 = 4095 - (s << 6); pst = -1; }
  else { p0 = 4095 - s;            pst = -64; }
  for (int i = 0; i < 64; i++){
    float u = xrow[(size_t)i*192];
    float acc = db;
    #pragma unroll
    for (int r = 0; r < 6; r++) acc += sdl[i*6 + r]*dw[r];
    float dl = fmaxf(acc, 0.f) + log1pf(__expf(-fabsf(acc)));
    float du = dl*u;
    float y = 0.f;
    if (fast){
      float e1 = __expf(-dl), e = 1.f;
      #pragma unroll
      for (int n = 0; n < 16; n++){
        e *= e1;
        h[n] = h[n]*e + du*sB[n][i];
        y += h[n]*sC[n][i];
      }
    } else {
      #pragma unroll
      for (int n = 0; n < 16; n++){
        float e = __expf(dl*A[n]);
        h[n] = h[n]*e + du*sB[n][i];
        y += h[n]*sC[n][i];
      }
    }
    y += u*Dc;
    atomicAdd(&yb[((size_t)b*4096 + p0 + pst*i)*192 + c], y);
  }
}

// ------------------------------------------------ K14b: symmetry enhance (atomic path)
__global__ __launch_bounds__(256) void k_enh(const float* __restrict__ yb,
    const float* __restrict__ symw, float* __restrict__ yfb){
  int id = blockIdx.x*256 + threadIdx.x;
  int c = id % 192; int rest = id / 192; int l = rest & 4095; int b = rest >> 12;
  int w = l & 63; int lr = (l | 63) - w;
  float v  = yb[id];
  float vr = yb[(((size_t)b << 12) + lr)*192 + c];
  float wg = 1.f/(1.f + __expf(-symw[0]));
  float enh = v*(1.f - wg) + 0.5f*(v + vr)*wg;
  yfb[id] = v + 0.2f*enh;
}

// ------------------------------------------------ K15a (fused, bigws)
__global__ __launch_bounds__(256) void k_final_comb(const float* __restrict__ Y,
    const float* __restrict__ symw, const float* __restrict__ zT,
    const float* __restrict__ g, const float* __restrict__ bta,
    const float* __restrict__ opw, const float* __restrict__ x, float* __restrict__ out){
  int og = blockIdx.x & 1; int lt = (blockIdx.x >> 1) & 127; int b = blockIdx.x >> 8;
  int l0 = lt << 5;
  __shared__ float sv[32][193];
  __shared__ float wt[192*48];
  __shared__ float sg[192], sb2[192];
  __shared__ float smu[32], srs[32];
  int tid = threadIdx.x;
  const size_t S = (size_t)4096*192;
  float wg = 1.f/(1.f + __expf(-symw[0]));
  for (int idx = tid; idx < 6144; idx += 256){
    int r = idx/192, cc = idx - r*192;
    int l = l0 + r; int w = l & 63; int lr = (l | 63) - w;
    size_t base = (size_t)b*S + cc;
    size_t o1 = base + (size_t)l*192, o2 = base + (size_t)lr*192;
    float v  = Y[o1] + Y[4*S + o1] + Y[8*S + o1] + Y[12*S + o1];
    float vr = Y[o2] + Y[4*S + o2] + Y[8*S + o2] + Y[12*S + o2];
    float enh = v*(1.f - wg) + 0.5f*(v + vr)*wg;
    sv[r][cc] = v + 0.2f*enh;
  }
  if (tid < 192){ sg[tid] = g[tid]; sb2[tid] = bta[tid]; }
  int o0 = og*48;
  for (int idx = tid; idx < 9216; idx += 256){ int o = idx % 48, c = idx/48;
    wt[c*48 + o] = opw[(size_t)(o0 + o)*192 + c]; }
  __syncthreads();
  if (tid < 32){
    float s1 = 0.f, s2 = 0.f;
    for (int c = 0; c < 192; c++){ float v = sv[tid][c]; s1 += v; s2 += v*v; }
    float mu = s1*(1.0f/192.0f);
    smu[tid] = mu; srs[tid] = rsqrtf(s2*(1.0f/192.0f) - mu*mu + 1e-5f);
  }
  __syncthreads();
  for (int idx = tid; idx < 6144; idx += 256){ int l = idx & 31, c = idx >> 5;
    float zv = zT[((size_t)b*192 + c)*4096 + l0 + l];
    float v = sv[l][c];
    float yn = (v - smu[l])*srs[l]*sg[c] + sb2[c];
    sv[l][c] = yn * (zv/(1.f + __expf(-zv)));
  }
  __syncthreads();
  int l = tid & 31, grp = tid >> 5;
  float acc[6];
  #pragma unroll
  for (int j = 0; j < 6; j++) acc[j] = 0.f;
  for (int c = 0; c < 192; c++){
    float svv = sv[l][c];
    const float* wr = &wt[c*48 + grp*6];
    #pragma unroll
    for (int j = 0; j < 6; j += 2){
      float2 w2 = *(const float2*)&wr[j];
      acc[j]   += svv*w2.x; acc[j+1] += svv*w2.y;
    }
  }
  size_t ob = ((size_t)b*4096 + l0 + l)*96 + o0 + grp*6;
  #pragma unroll
  for (int j = 0; j < 6; j++) acc[j] += x[ob + j];
  #pragma unroll
  for (int j = 0; j < 6; j += 2){
    float2 v2; v2.x = acc[j]; v2.y = acc[j+1];
    *(float2*)&out[ob + j] = v2;
  }
}

// ------------------------------------------------ K15b: fallback
__global__ __launch_bounds__(256) void k_final(const float* __restrict__ yf,
    const float* __restrict__ zT, const float* __restrict__ g, const float* __restrict__ bta,
    const float* __restrict__ opw, const float* __restrict__ x, float* __restrict__ out){
  int og = blockIdx.x & 1; int lt = (blockIdx.x >> 1) & 127; int b = blockIdx.x >> 8;
  int l0 = lt << 5;
  __shared__ float sv[32][193];
  __shared__ float wt[192*48];
  __shared__ float sg[192], sb2[192];
  __shared__ float smu[32], srs[32];
  int tid = threadIdx.x;
  for (int idx = tid; idx < 6144; idx += 256){ int r = idx/192, c = idx - r*192;
    sv[r][c] = yf[((size_t)b*4096 + l0 + r)*192 + c]; }
  if (tid < 192){ sg[tid] = g[tid]; sb2[tid] = bta[tid]; }
  int o0 = og*48;
  for (int idx = tid; idx < 9216; idx += 256){ int o = idx % 48, c = idx/48;
    wt[c*48 + o] = opw[(size_t)(o0 + o)*192 + c]; }
  __syncthreads();
  if (tid < 32){
    float s1 = 0.f, s2 = 0.f;
    for (int c = 0; c < 192; c++){ float v = sv[tid][c]; s1 += v; s2 += v*v; }
    float mu = s1*(1.0f/192.0f);
    smu[tid] = mu; srs[tid] = rsqrtf(s2*(1.0f/192.0f) - mu*mu + 1e-5f);
  }
  __syncthreads();
  for (int idx = tid; idx < 6144; idx += 256){ int l = idx & 31, c = idx >> 5;
    float zv = zT[((size_t)b*192 + c)*4096 + l0 + l];
    float v = sv[l][c];
    float yn = (v - smu[l])*srs[l]*sg[c] + sb2[c];
    sv[l][c] = yn * (zv/(1.f + __expf(-zv)));
  }
  __syncthreads();
  int l = tid & 31, grp = tid >> 5;
  float acc[6];
  #pragma unroll
  for (int j = 0; j < 6; j++) acc[j] = 0.f;
  for (int c = 0; c < 192; c++){
    float svv = sv[l][c];
    const float* wr = &wt[c*48 + grp*6];
    #pragma unroll
    for (int j = 0; j < 6; j += 2){
      float2 w2 = *(const float2*)&wr[j];
      acc[j]   += svv*w2.x; acc[j+1] += svv*w2.y;
    }
  }
  size_t ob = ((size_t)b*4096 + l0 + l)*96 + o0 + grp*6;
  #pragma unroll
  for (int j = 0; j < 6; j++) acc[j] += x[ob + j];
  #pragma unroll
  for (int j = 0; j < 6; j += 2){
    float2 v2; v2.x = acc[j]; v2.y = acc[j+1];
    *(float2*)&out[ob + j] = v2;
  }
}

// ================================================================ host
extern "C" void kernel_launch(void* const* d_in, const int* in_sizes, int n_in,
                              void* d_out, int out_size, void* d_ws, size_t ws_size,
                              hipStream_t stream){
  (void)in_sizes; (void)n_in; (void)out_size;
  const float* ix   = (const float*)d_in[0];
  const float* ipw  = (const float*)d_in[1];
  const float* fw1  = (const float*)d_in[2];
  const float* fb1  = (const float*)d_in[3];
  const float* fw2  = (const float*)d_in[4];
  const float* fb2  = (const float*)d_in[5];
  const float* ww   = (const float*)d_in[6];
  const float* wb   = (const float*)d_in[7];
  const float* dww  = (const float*)d_in[8];
  const float* dwb  = (const float*)d_in[9];
  const float* symw = (const float*)d_in[10];
  const float* xpw  = (const float*)d_in[11];
  const float* dtw  = (const float*)d_in[12];
  const float* dtb  = (const float*)d_in[13];
  const float* alog = (const float*)d_in[14];
  const float* Dsp  = (const float*)d_in[15];
  const float* ong  = (const float*)d_in[16];
  const float* onb  = (const float*)d_in[17];
  const float* opw  = (const float*)d_in[18];
  const float* rmsw = (const float*)d_in[19];

  float* W = (float*)d_ws;
  const size_t SZ_BLC = 3145728, SZ_F = 1622016, SZ_H = 786432;
  float* zT  = W;
  float* ab  = zT + SZ_BLC;
  float* R0  = ab + SZ_BLC;
  // phase 1
  float* xc    = R0;
  float* fre   = xc  + SZ_BLC;
  float* fim   = fre + SZ_F;
  float* fab   = fim + SZ_F;
  float* mb    = fab + SZ_F;
  float* llb   = mb  + SZ_F;
  float* lhb   = llb + SZ_H;                 // lh,hl,hh = 3*SZ_H fp32
  float* wnew  = lhb + 3*SZ_H;               // 2,359,296 fp32 (full-K conv out)
  unsigned short* pb2  = (unsigned short*)(wnew + 2359296);   // 2,662,912 bf16
  unsigned short* wqb2 = pb2 + 2662912;                       //   331,776 bf16
  // phase 2
  float* Bsb  = R0;
  float* Csb  = Bsb + 1048576;
  float* dlsb = Csb + 1048576;
  float* xsb  = dlsb + 393216;
  float* Pb   = xsb + 12582912;
  float* aT   = Pb;
  float* Qb   = Pb + SZ_BLC;
  float* Yb   = Qb;
  float* ybA  = Qb + SZ_BLC;
  float* yfb  = xsb;

  const size_t NEED_BIG = (size_t)(6291456 + 30801920) * 4;
  bool bigws = (ws_size >= NEED_BIG);

  hipLaunchKernelGGL(k_rms_inproj, dim3(2048),   dim3(256), 0, stream, ix, rmsw, ipw, xc, zT);
  hipLaunchKernelGGL(k_dft_fwd,    dim3(4*192),  dim3(256), 0, stream, xc, fre, fim, fab,
                     llb, lhb, lhb + SZ_H, lhb + 2*SZ_H);
  hipLaunchKernelGGL(k_cvt_in,     dim3(10402),  dim3(256), 0, stream, lhb, pb2, 2662912);
  hipLaunchKernelGGL(k_cvt_w,      dim3(1296),   dim3(256), 0, stream, ww, wqb2);
  hipLaunchKernelGGL(k_cmix1,      dim3(864),    dim3(256), 0, stream, fab, fw1, fb1, mb);
  hipLaunchKernelGGL(k_cmix2,      dim3(864),    dim3(256), 0, stream, mb, fw2, fb2, fre, fim, fab);
  hipLaunchKernelGGL(k_wconv_mfma, dim3(576),    dim3(256), 0, stream, pb2, wqb2, wnew);
  hipLaunchKernelGGL(k_ifwd,       dim3(768),    dim3(256), 0, stream, fre, fim, xc, llb, wnew, wb, dww, dwb, ab, aT);
  hipLaunchKernelGGL(k_xproj,      dim3(1024),   dim3(256), 0, stream, ab, aT, xpw, Bsb, Csb, dlsb, xsb);
  hipLaunchKernelGGL(k_scanA,      dim3(1024),   dim3(192), 0, stream, xsb, dlsb, Bsb, dtw, dtb, alog, Pb, Qb);
  hipLaunchKernelGGL(k_scanB,      dim3(192),    dim3(256), 0, stream, Pb, Qb);
  if (bigws){
    hipLaunchKernelGGL(k_scanC_buf,  dim3(1024), dim3(192), 0, stream, xsb, dlsb, Bsb, Csb, Pb, dtw, dtb, alog, Dsp, Yb);
    hipLaunchKernelGGL(k_final_comb, dim3(1024), dim3(256), 0, stream, Yb, symw, zT, ong, onb, opw, ix, (float*)d_out);
  } else {
    hipLaunchKernelGGL(k_zero,       dim3(12288), dim3(256), 0, stream, ybA, (int)SZ_BLC);
    hipLaunchKernelGGL(k_scanC_atom, dim3(1024),  dim3(192), 0, stream, xsb, dlsb, Bsb, Csb, Pb, dtw, dtb, alog, Dsp, ybA);
    hipLaunchKernelGGL(k_enh,        dim3(12288), dim3(256), 0, stream, ybA, symw, yfb);
    hipLaunchKernelGGL(k_final,      dim3(1024),  dim3(256), 0, stream, yfb, zT, ong, onb, opw, ix, (float*)d_out);
  }
}

// Round 13
// 765.059 us; speedup vs baseline: 1.0872x; 1.0691x over previous
//
#include <hip/hip_runtime.h>
#include <hip/hip_bf16.h>

#define CI 192
#define LL_ 4096

typedef __bf16 v8bf __attribute__((ext_vector_type(8)));
typedef float  v4f  __attribute__((ext_vector_type(4)));
typedef unsigned short v8us __attribute__((ext_vector_type(8)));

__device__ __forceinline__ unsigned short f2bf(float v){
  unsigned int u = __float_as_uint(v);
  return (unsigned short)((u + 0x7FFFu + ((u >> 16) & 1u)) >> 16);
}

__global__ __launch_bounds__(256) void k_zero(float* __restrict__ p, int n){
  int i = blockIdx.x*256 + threadIdx.x;
  if (i < n) p[i] = 0.f;
}

// ------------------------------------------------ K1: RMSNorm + in_proj (tiled GEMM, 48-o tiles)
__global__ __launch_bounds__(256) void k_rms_inproj(const float* __restrict__ x,
    const float* __restrict__ rmsw, const float* __restrict__ ipw,
    float* __restrict__ xc, float* __restrict__ zT){
  int og = blockIdx.x & 7; int lt = (blockIdx.x >> 3) & 63; int b = blockIdx.x >> 9;
  int l0 = lt << 6;
  __shared__ float xt[64][97];
  __shared__ float wt[96*48];
  __shared__ float rr[64];
  __shared__ float rw[96];
  int tid = threadIdx.x;
  for (int idx = tid; idx < 6144; idx += 256){ int r = idx/96, d = idx - r*96;
    xt[r][d] = x[((size_t)b*4096 + l0 + r)*96 + d]; }
  if (tid < 96) rw[tid] = rmsw[tid];
  int o0 = og*48;
  for (int idx = tid; idx < 4608; idx += 256){ int o = idx%48, d = idx/48;
    wt[d*48 + o] = ipw[(size_t)(o0 + o)*96 + d]; }
  __syncthreads();
  if (tid < 64){
    float s = 0.f;
    for (int d = 0; d < 96; d++){ float v = xt[tid][d]; s += v*v; }
    rr[tid] = rsqrtf(s*(1.0f/96.0f) + 1e-5f);
  }
  __syncthreads();
  for (int idx = tid; idx < 6144; idx += 256){ int r = idx/96, d = idx - r*96;
    xt[r][d] *= rr[r]*rw[d]; }
  __syncthreads();
  int l = tid & 63, grp = tid >> 6;
  float acc[12];
  #pragma unroll
  for (int j = 0; j < 12; j++) acc[j] = 0.f;
  for (int d = 0; d < 96; d++){
    float xv = xt[l][d];
    const float* wr = &wt[d*48 + grp*12];
    #pragma unroll
    for (int j = 0; j < 12; j += 4){
      float4 w4 = *(const float4*)&wr[j];
      acc[j]   += xv*w4.x; acc[j+1] += xv*w4.y;
      acc[j+2] += xv*w4.z; acc[j+3] += xv*w4.w;
    }
  }
  #pragma unroll
  for (int j = 0; j < 12; j++){
    int o = o0 + grp*12 + j;
    if (o < 192) xc[((size_t)b*192 + o)*4096 + l0 + l] = acc[j];
    else         zT[((size_t)b*192 + (o-192))*4096 + l0 + l] = acc[j];
  }
}

// ------------------------------------------------ K2: forward rfft2 (ortho) + fused Haar DWT
__global__ __launch_bounds__(256) void k_dft_fwd(const float* __restrict__ xc,
    float* __restrict__ fre, float* __restrict__ fim, float* __restrict__ fab,
    float* __restrict__ ll, float* __restrict__ lh, float* __restrict__ hl, float* __restrict__ hh){
  int plane = blockIdx.x;
  __shared__ float sxT[64*65];
  __shared__ float t1r[64*34], t1i[64*34];
  __shared__ float tabr[16], tabi[16];
  __shared__ float ct64[64], st64[64];
  int tid = threadIdx.x;
  const float* X = xc + (size_t)plane*4096;
  for (int i = tid; i < 4096; i += 256){ int h = i >> 6, w = i & 63; sxT[w*65 + h] = X[i]; }
  if (tid < 16){ tabr[tid] = cospif((float)tid/8.0f); tabi[tid] = -sinpif((float)tid/8.0f); }
  if (tid < 64){ ct64[tid] = cospif((float)tid/32.0f); st64[tid] = sinpif((float)tid/32.0f); }
  __syncthreads();
  {
    size_t qbase = (size_t)plane*1024;
    for (int idx = tid; idx < 1024; idx += 256){
      int y2 = idx >> 5, x2 = idx & 31;
      float a_ = sxT[(2*x2)*65 + 2*y2],     b_ = sxT[(2*x2+1)*65 + 2*y2];
      float c_ = sxT[(2*x2)*65 + 2*y2+1],   d_ = sxT[(2*x2+1)*65 + 2*y2+1];
      ll[qbase + idx] = (a_+b_+c_+d_)*0.5f; lh[qbase + idx] = (a_-b_+c_-d_)*0.5f;
      hl[qbase + idx] = (a_+b_-c_-d_)*0.5f; hh[qbase + idx] = (a_-b_-c_+d_)*0.5f;
    }
  }
  {
    int hp = tid & 31, g = tid >> 5;
    float a0r[4], a0i[4], a1r[4], a1i[4];
    #pragma unroll
    for (int j = 0; j < 4; j++){ a0r[j]=0.f; a0i[j]=0.f; a1r[j]=0.f; a1i[j]=0.f; }
    float s32_0 = 0.f, s32_1 = 0.f;
    for (int w = 0; w < 64; w++){
      float xv0 = sxT[w*65 + hp];
      float xv1 = sxT[w*65 + hp + 32];
      int m0 = (w*g) & 15;
      float twr = tabr[m0], twi = tabi[m0];
      int ms = w & 15;
      float str = tabr[ms], sti = tabi[ms];
      #pragma unroll
      for (int j = 0; j < 4; j++){
        a0r[j] += xv0*twr; a0i[j] += xv0*twi;
        a1r[j] += xv1*twr; a1i[j] += xv1*twi;
        float nr = twr*str - twi*sti;
        float ni = twr*sti + twi*str;
        twr = nr; twi = ni;
      }
      if (g == 0){ float sg = (w & 1) ? -1.f : 1.f; s32_0 += xv0*sg; s32_1 += xv1*sg; }
    }
    #pragma unroll
    for (int j = 0; j < 4; j++){
      int k = 4*g + j;
      t1r[hp*34 + k] = a0r[j];        t1i[hp*34 + k] = a0i[j];
      t1r[(hp+32)*34 + k] = a1r[j];   t1i[(hp+32)*34 + k] = a1i[j];
    }
    if (g == 0){
      t1r[hp*34 + 32] = s32_0;      t1i[hp*34 + 32] = 0.f;
      t1r[(hp+32)*34 + 32] = s32_1; t1i[(hp+32)*34 + 32] = 0.f;
    }
  }
  __syncthreads();
  {
    int fp = tid & 31, g = tid >> 5;
    float stepr = cospif((float)fp/32.0f), stepi = -sinpif((float)fp/32.0f);
    float a0r[4], a0i[4], a1r[4], a1i[4];
    #pragma unroll
    for (int j = 0; j < 4; j++){ a0r[j]=0.f; a0i[j]=0.f; a1r[j]=0.f; a1i[j]=0.f; }
    float b0r=0.f, b0i=0.f, b1r=0.f, b1i=0.f;
    for (int hb = 0; hb < 4; hb++){
      int m = ((hb*16)*fp) & 63;
      float twr = ct64[m], twi = -st64[m];
      for (int hh2 = 0; hh2 < 16; hh2++){
        int h = hb*16 + hh2;
        float sg = (h & 1) ? -1.f : 1.f;
        #pragma unroll
        for (int j = 0; j < 4; j++){
          float Tr = t1r[h*34 + 4*g + j], Ti = t1i[h*34 + 4*g + j];
          float pr = Tr*twr - Ti*twi;
          float pi = Tr*twi + Ti*twr;
          a0r[j] += pr; a0i[j] += pi;
          a1r[j] += sg*pr; a1i[j] += sg*pi;
        }
        if (g == 0){
          float Tr = t1r[h*34 + 32], Ti = t1i[h*34 + 32];
          float pr = Tr*twr - Ti*twi, pi = Tr*twi + Ti*twr;
          b0r += pr; b0i += pi; b1r += sg*pr; b1i += sg*pi;
        }
        float nr = twr*stepr - twi*stepi, ni = twr*stepi + twi*stepr;
        twr = nr; twi = ni;
      }
    }
    size_t base = (size_t)plane*2112;
    #pragma unroll
    for (int j = 0; j < 4; j++){
      int k = 4*g + j;
      float r0 = a0r[j]*(1.f/64.f), i0 = a0i[j]*(1.f/64.f);
      float r1 = a1r[j]*(1.f/64.f), i1 = a1i[j]*(1.f/64.f);
      fre[base + fp*33 + k] = r0; fim[base + fp*33 + k] = i0;
      fab[base + fp*33 + k] = sqrtf(r0*r0 + i0*i0);
      fre[base + (fp+32)*33 + k] = r1; fim[base + (fp+32)*33 + k] = i1;
      fab[base + (fp+32)*33 + k] = sqrtf(r1*r1 + i1*i1);
    }
    if (g == 0){
      float r0 = b0r*(1.f/64.f), i0 = b0i*(1.f/64.f);
      float r1 = b1r*(1.f/64.f), i1 = b1i*(1.f/64.f);
      fre[base + fp*33 + 32] = r0; fim[base + fp*33 + 32] = i0;
      fab[base + fp*33 + 32] = sqrtf(r0*r0 + i0*i0);
      fre[base + (fp+32)*33 + 32] = r1; fim[base + (fp+32)*33 + 32] = i1;
      fab[base + (fp+32)*33 + 32] = sqrtf(r1*r1 + i1*i1);
    }
  }
}

// ------------------------------------------------ K3: m = gelu(W1 @ |xf| + b1)  (LDS weights)
__global__ __launch_bounds__(256) void k_cmix1(const float* __restrict__ fab,
    const float* __restrict__ w1, const float* __restrict__ b1, float* __restrict__ m){
  int bid = blockIdx.x;
  int pt = bid % 9; int og = (bid/9) % 24; int b = bid/216;
  int tid = threadIdx.x;
  int p = pt*256 + tid; bool act = p < 2112;
  __shared__ float wl[192*8];
  for (int idx = tid; idx < 1536; idx += 256){ int o = idx & 7, c = idx >> 3;
    wl[c*8 + o] = w1[(size_t)(og*8 + o)*192 + c]; }
  __syncthreads();
  float acc[8];
  #pragma unroll
  for (int o = 0; o < 8; o++) acc[o] = b1[og*8 + o];
  const float* xb = fab + (size_t)b*CI*2112 + p;
  for (int c = 0; c < 192; c++){
    float xv = act ? xb[(size_t)c*2112] : 0.f;
    float4 wa = *(const float4*)&wl[c*8];
    float4 wb4 = *(const float4*)&wl[c*8 + 4];
    acc[0] += xv*wa.x;  acc[1] += xv*wa.y;  acc[2] += xv*wa.z;  acc[3] += xv*wa.w;
    acc[4] += xv*wb4.x; acc[5] += xv*wb4.y; acc[6] += xv*wb4.z; acc[7] += xv*wb4.w;
  }
  if (act){
    #pragma unroll
    for (int o = 0; o < 8; o++){
      float a = acc[o];
      m[((size_t)b*192 + og*8 + o)*2112 + p] = 0.5f*a*(1.0f + erff(a*0.70710678118654752f));
    }
  }
}

// ------------------------------------------------ K4: mag = W2 @ m + b2; in-place (LDS weights)
__global__ __launch_bounds__(256) void k_cmix2(const float* __restrict__ m,
    const float* __restrict__ w2, const float* __restrict__ bi2,
    float* __restrict__ fre, float* __restrict__ fim, const float* __restrict__ fab){
  int bid = blockIdx.x;
  int pt = bid % 9; int og = (bid/9) % 24; int b = bid/216;
  int tid = threadIdx.x;
  int p = pt*256 + tid; bool act = p < 2112;
  __shared__ float wl[192*8];
  for (int idx = tid; idx < 1536; idx += 256){ int o = idx & 7, c = idx >> 3;
    wl[c*8 + o] = w2[(size_t)(og*8 + o)*192 + c]; }
  __syncthreads();
  float acc[8];
  #pragma unroll
  for (int o = 0; o < 8; o++) acc[o] = bi2[og*8 + o];
  const float* xb = m + (size_t)b*CI*2112 + p;
  for (int c = 0; c < 192; c++){
    float xv = act ? xb[(size_t)c*2112] : 0.f;
    float4 wa = *(const float4*)&wl[c*8];
    float4 wb4 = *(const float4*)&wl[c*8 + 4];
    acc[0] += xv*wa.x;  acc[1] += xv*wa.y;  acc[2] += xv*wa.z;  acc[3] += xv*wa.w;
    acc[4] += xv*wb4.x; acc[5] += xv*wb4.y; acc[6] += xv*wb4.z; acc[7] += xv*wb4.w;
  }
  if (act){
    #pragma unroll
    for (int o = 0; o < 8; o++){
      size_t id = ((size_t)b*192 + og*8 + o)*2112 + p;
      float ab = fab[id];
      float re, im;
      if (ab > 1e-30f){ float sc = acc[o]/ab; re = sc*fre[id]; im = sc*fim[id]; }
      else { re = acc[o]; im = 0.f; }
      fre[id] = re; fim[id] = im;
    }
  }
}

// ------------------------------------------------ K5b: convert weights -> bf16 [q][oc][ic]
__global__ __launch_bounds__(256) void k_cvt_w(const float* __restrict__ ww,
    unsigned short* __restrict__ wqb2){
  int idx = blockIdx.x*256 + threadIdx.x;
  if (idx >= 331776) return;
  int ic = idx % 192; int rest = idx / 192;
  int oc = rest % 192; int q = rest / 192;
  wqb2[idx] = f2bf(ww[((size_t)oc*192 + ic)*9 + q]);
}

// ------------------------------------------------ K6: 3x3 full conv via bf16 MFMA, A staged once
// grid 576: nt(3: 64 oc) x mt(16: 64 spatial) x img(12, slowest)
__global__ __launch_bounds__(256) void k_wconv_mfma(const float* __restrict__ lhb,
    const unsigned short* __restrict__ wqb2, float* __restrict__ wnew){
  int bid = blockIdx.x;
  int nt = bid % 3; int mt = (bid/3) & 15; int img = bid/48;
  int o0 = nt*64;
  __shared__ __align__(16) unsigned short sm_us[40000];  // 80 KB
  unsigned short* Aband = sm_us;            // [4 row][34 col] x stride 200 (192 ic used)
  unsigned short* Bbuf  = sm_us + 27200;    // [64 oc] x stride 200
  float* T = (float*)sm_us;                 // epilogue [64 m][65] = 16.6 KB
  int tid = threadIdx.x;
  int lane = tid & 63, wv = tid >> 6;
  int quad = lane >> 4, n16 = lane & 15;
  const float* base = lhb + (size_t)img*196608;
  // stage A band once: rows 2mt-1..2mt+2 (padded band rows 0..3), cols -1..32, 192 ic
  for (int idx = tid; idx < 26112; idx += 256){
    int pix = idx % 136;           // r*34 + col
    int ic  = idx / 136;
    int r = pix / 34, col = pix - r*34;
    int gr = 2*mt - 1 + r, gc = col - 1;
    float v = (gr >= 0 && gr < 32 && gc >= 0 && gc < 32) ? base[(size_t)ic*1024 + gr*32 + gc] : 0.f;
    Aband[pix*200 + ic] = f2bf(v);
  }
  v4f acc[4];
  #pragma unroll
  for (int t2 = 0; t2 < 4; t2++) acc[t2] = (v4f){0.f,0.f,0.f,0.f};
  for (int q = 0; q < 9; q++){
    int ky = q/3, kx = q - ky*3;
    if (q) __syncthreads();                    // previous compute done before B overwrite
    // stage B [64 oc][192 ic], 16B vector loads
    for (int idx = tid; idx < 1536; idx += 256){
      int oc = idx / 24, g = idx - (idx/24)*24;
      v8us wv8 = *(const v8us*)&wqb2[((size_t)(q*192) + o0 + oc)*192 + g*8];
      *(v8us*)&Bbuf[oc*200 + g*8] = wv8;
    }
    __syncthreads();
    #pragma unroll
    for (int icc = 0; icc < 6; icc++){
      int c0 = icc*32;
      v8us bu = *(const v8us*)&Bbuf[(16*wv + n16)*200 + c0 + quad*8];
      v8bf bv = __builtin_bit_cast(v8bf, bu);
      #pragma unroll
      for (int t2 = 0; t2 < 4; t2++){
        int mm = t2*16 + n16;
        int pix = ((mm >> 5) + ky)*34 + (mm & 31) + kx;
        v8us au = *(const v8us*)&Aband[pix*200 + c0 + quad*8];
        v8bf av = __builtin_bit_cast(v8bf, au);
        acc[t2] = __builtin_amdgcn_mfma_f32_16x16x32_bf16(av, bv, acc[t2], 0, 0, 0);
      }
    }
  }
  __syncthreads();
  // epilogue: regs -> T[64 m][65] -> coalesced store (wnew[img][oc][1024])
  #pragma unroll
  for (int t2 = 0; t2 < 4; t2++)
    #pragma unroll
    for (int r = 0; r < 4; r++)
      T[(16*t2 + quad*4 + r)*65 + 16*wv + n16] = acc[t2][r];
  __syncthreads();
  float* outb = wnew + (size_t)img*196608;
  for (int idx = tid; idx < 4096; idx += 256){
    int mm = idx & 63, oc = idx >> 6;
    outb[(size_t)(o0 + oc)*1024 + mt*64 + mm] = T[mm*65 + oc];
  }
}

// ------------------------------------------------ K7 (fused): irfft2 + combine + depthwise3x3 + SiLU -> ab, aT
__global__ __launch_bounds__(256) void k_ifwd(const float* __restrict__ fre2,
    const float* __restrict__ fim2, const float* __restrict__ xc,
    const float* __restrict__ ll, const float* __restrict__ wnew, const float* __restrict__ wb,
    const float* __restrict__ dww, const float* __restrict__ dwb,
    float* __restrict__ ab, float* __restrict__ aT){
  int plane = blockIdx.x;
  int c = plane % 192;
  __shared__ float sm[12936];
  float* gr  = sm;
  float* gi  = sm + 2176;
  float* ur  = sm + 4352;
  float* ui  = sm + 6528;
  float* sx2 = sm + 8704;
  float* t64r = sm + 12800; float* t64i = sm + 12864;
  float* t4r  = sm + 12928; float* t4i  = sm + 12932;
  float* scratch = sm;
  int tid = threadIdx.x;
  for (int i = tid; i < 2112; i += 256){
    size_t o = (size_t)plane*2112 + i;
    int f = i/33, k = i - f*33;
    gr[f*34 + k] = fre2[o]; gi[f*34 + k] = fim2[o];
  }
  if (tid < 64){ t64r[tid] = cospif((float)tid/32.0f); t64i[tid] = sinpif((float)tid/32.0f); }
  if (tid < 4){ t4r[tid] = (tid == 0) ? 1.f : ((tid == 2) ? -1.f : 0.f);
                t4i[tid] = (tid == 1) ? 1.f : ((tid == 3) ? -1.f : 0.f); }
  __syncthreads();
  {
    int hp = tid & 31, g = tid >> 5;
    float stepr = cospif((float)hp/32.0f), stepi = sinpif((float)hp/32.0f);
    float a0r[4], a0i[4], a1r[4], a1i[4];
    #pragma unroll
    for (int j = 0; j < 4; j++){ a0r[j]=0.f; a0i[j]=0.f; a1r[j]=0.f; a1i[j]=0.f; }
    float b0r=0.f, b0i=0.f, b1r=0.f, b1i=0.f;
    for (int fb = 0; fb < 4; fb++){
      int m = ((fb*16)*hp) & 63;
      float twr = t64r[m], twi = t64i[m];
      for (int ff = 0; ff < 16; ff++){
        int f = fb*16 + ff;
        float sg = (f & 1) ? -1.f : 1.f;
        #pragma unroll
        for (int j = 0; j < 4; j++){
          float Gr = gr[f*34 + 4*g + j], Gi = gi[f*34 + 4*g + j];
          float pr = Gr*twr - Gi*twi;
          float pi = Gr*twi + Gi*twr;
          a0r[j] += pr; a0i[j] += pi;
          a1r[j] += sg*pr; a1i[j] += sg*pi;
        }
        if (g == 0){
          float Gr = gr[f*34 + 32], Gi = gi[f*34 + 32];
          float pr = Gr*twr - Gi*twi, pi = Gr*twi + Gi*twr;
          b0r += pr; b0i += pi; b1r += sg*pr; b1i += sg*pi;
        }
        float nr = twr*stepr - twi*stepi, ni = twr*stepi + twi*stepr;
        twr = nr; twi = ni;
      }
    }
    __syncthreads();
    #pragma unroll
    for (int j = 0; j < 4; j++){
      int k = 4*g + j;
      float ck = (k == 0) ? (1.f/64.f) : (2.f/64.f);
      ur[hp*34 + k] = a0r[j]*ck;       ui[hp*34 + k] = a0i[j]*ck;
      ur[(hp+32)*34 + k] = a1r[j]*ck;  ui[(hp+32)*34 + k] = a1i[j]*ck;
    }
    if (g == 0){
      ur[hp*34 + 32] = b0r*(1.f/64.f);      ui[hp*34 + 32] = b0i*(1.f/64.f);
      ur[(hp+32)*34 + 32] = b1r*(1.f/64.f); ui[(hp+32)*34 + 32] = b1i*(1.f/64.f);
    }
  }
  __syncthreads();
  {
    int h = tid & 63, wg = tid >> 6;
    float acc[16];
    #pragma unroll
    for (int j = 0; j < 16; j++) acc[j] = 0.f;
    for (int k = 0; k <= 32; k++){
      float Ur = ur[h*34 + k], Ui = ui[h*34 + k];
      int m = (k*wg) & 3;
      float twr = t4r[m], twi = t4i[m];
      float str = t64r[k], sti = t64i[k];
      #pragma unroll
      for (int j = 0; j < 16; j++){
        acc[j] += Ur*twr - Ui*twi;
        float nr = twr*str - twi*sti, ni = twr*sti + twi*str;
        twr = nr; twi = ni;
      }
    }
    #pragma unroll
    for (int j = 0; j < 16; j++) sx2[h*64 + 16*wg + j] = acc[j];
  }
  __syncthreads();
  float bia = wb[c];
  for (int p = tid; p < 4096; p += 256){
    int h = p >> 6, w = p & 63;
    size_t q = (size_t)plane*1024 + (size_t)(h >> 1)*32 + (w >> 1);
    float LLv = ll[q];
    float LH = wnew[q] + bia;
    float HL = wnew[786432 + q] + bia;
    float HH = wnew[1572864 + q] + bia;
    float v;
    bool hb = (h & 1), wbit = (w & 1);
    if (!hb && !wbit)      v = (LLv + LH + HL + HH)*0.5f;
    else if (!hb && wbit)  v = (LLv - LH + HL - HH)*0.5f;
    else if (hb && !wbit)  v = (LLv + LH - HL - HH)*0.5f;
    else                   v = (LLv - LH - HL + HH)*0.5f;
    sx2[p] = 2.0f*xc[(size_t)plane*4096 + p] + sx2[p] + v;
  }
  __syncthreads();
  float wk[9];
  #pragma unroll
  for (int q = 0; q < 9; q++) wk[q] = dww[c*9 + q];
  float dbv = dwb[c];
  for (int p = tid; p < 4096; p += 256){
    int h = p >> 6, w = p & 63;
    float acc = dbv;
    #pragma unroll
    for (int ky = 0; ky < 3; ky++){
      int yy = h + ky - 1; if (yy < 0 || yy > 63) continue;
      #pragma unroll
      for (int kx = 0; kx < 3; kx++){
        int xx = w + kx - 1; if (xx < 0 || xx > 63) continue;
        acc += sx2[yy*64 + xx]*wk[ky*3 + kx];
      }
    }
    scratch[h*65 + w] = acc / (1.f + __expf(-acc));
  }
  __syncthreads();
  float* abp = ab + (size_t)plane*4096;
  float* aTp = aT + (size_t)plane*4096;
  for (int p = tid; p < 4096; p += 256){
    abp[p] = scratch[(p >> 6)*65 + (p & 63)];
    aTp[p] = scratch[(p & 63)*65 + (p >> 6)];
  }
}

// ------------------------------------------------ K10: x_proj; wave-split GEMM
__global__ __launch_bounds__(256) void k_xproj(const float* __restrict__ ab,
    const float* __restrict__ aT, const float* __restrict__ xpw,
    float* __restrict__ Bsb, float* __restrict__ Csb, float* __restrict__ dlsb,
    float* __restrict__ xsb){
  int bid = blockIdx.x;
  int s = bid & 63; int k = (bid >> 6) & 3; int b = bid >> 8;
  int tid = threadIdx.x;
  __shared__ float als[192][65];
  __shared__ float dls[6][64];
  int l0 = s << 6;
  const float* src = (k & 1) ? aT : ab;
  int off0 = (k < 2) ? l0 : (4095 - l0);
  int stp  = (k < 2) ? 1 : -1;
  for (int idx = tid; idx < 192*64; idx += 256){
    int d = idx >> 6, i = idx & 63;
    als[d][i] = src[((size_t)b*192 + d)*4096 + off0 + stp*i];
  }
  __syncthreads();
  {
    int i = tid & 63, wg = tid >> 6;
    const float* wr[10];
    #pragma unroll
    for (int r = 0; r < 10; r++){
      int cp = wg + 4*r; if (cp > 37) cp = 37;
      wr[r] = xpw + ((size_t)k*38 + cp)*192;
    }
    float acc[10];
    #pragma unroll
    for (int r = 0; r < 10; r++) acc[r] = 0.f;
    for (int d = 0; d < 192; d++){
      float v = als[d][i];
      #pragma unroll
      for (int r = 0; r < 10; r++) acc[r] += v*wr[r][d];
    }
    #pragma unroll
    for (int r = 0; r < 10; r++){
      int cp = wg + 4*r;
      if (cp > 37) continue;
      if (cp < 6) dls[cp][i] = acc[r];
      else if (cp < 22) Bsb[((size_t)(b*4 + k)*16 + (cp - 6 ))*4096 + l0 + i] = acc[r];
      else              Csb[((size_t)(b*4 + k)*16 + (cp - 22))*4096 + l0 + i] = acc[r];
    }
  }
  size_t xbase = ((size_t)(b*4 + k)*4096 + l0)*192;
  for (int j = tid; j < 192*64; j += 256){
    int i = j / 192, c = j % 192;
    xsb[xbase + (size_t)i*192 + c] = als[c][i];
  }
  __syncthreads();
  size_t dbase = (size_t)((b*4 + k)*64 + s)*384;
  for (int j = tid; j < 384; j += 256){
    int i = j/6, r = j - i*6;
    dlsb[dbase + j] = dls[r][i];
  }
}

// ------------------------------------------------ K11: scan phase A (fast-exp)
__global__ __launch_bounds__(192) void k_scanA(const float* __restrict__ xsb,
    const float* __restrict__ dlsb, const float* __restrict__ Bsb,
    const float* __restrict__ dtw, const float* __restrict__ dtb,
    const float* __restrict__ alog, float* __restrict__ Pb, float* __restrict__ Qb){
  int bid = blockIdx.x; int s = bid & 63; int k = (bid >> 6) & 3; int b = bid >> 8;
  int c = threadIdx.x; int bk = b*4 + k;
  __shared__ float sdl[384];
  __shared__ float sB[16][64];
  size_t dbase = (size_t)(bk*64 + s)*384;
  for (int j = c; j < 384; j += 192) sdl[j] = dlsb[dbase + j];
  for (int j = c; j < 1024; j += 192){ int n = j >> 6, i = j & 63;
    sB[n][i] = Bsb[((size_t)bk*16 + n)*4096 + (s << 6) + i]; }
  __syncthreads();
  float A[16], P[16], Q[16];
  const float* arow = alog + ((size_t)k*192 + c)*16;
  bool fast = true;
  #pragma unroll
  for (int n = 0; n < 16; n++){
    A[n] = -__expf(arow[n]); P[n] = 1.f; Q[n] = 0.f;
    if (fabsf(A[n] + (float)(n+1)) > 1e-3f) fast = false;
  }
  float dw[6];
  #pragma unroll
  for (int r = 0; r < 6; r++) dw[r] = dtw[((size_t)k*192 + c)*6 + r];
  float db = dtb[k*192 + c];
  const float* xrow = xsb + ((size_t)bk*4096 + (s << 6))*192 + c;
  if (fast){
    for (int i = 0; i < 64; i++){
      float u = xrow[(size_t)i*192];
      float acc = db;
      #pragma unroll
      for (int r = 0; r < 6; r++) acc += sdl[i*6 + r]*dw[r];
      float dl = fmaxf(acc, 0.f) + log1pf(__expf(-fabsf(acc)));
      float du = dl*u;
      float e1 = __expf(-dl), e = 1.f;
      #pragma unroll
      for (int n = 0; n < 16; n++){
        e *= e1;
        P[n] *= e;
        Q[n] = Q[n]*e + du*sB[n][i];
      }
    }
  } else {
    for (int i = 0; i < 64; i++){
      float u = xrow[(size_t)i*192];
      float acc = db;
      #pragma unroll
      for (int r = 0; r < 6; r++) acc += sdl[i*6 + r]*dw[r];
      float dl = fmaxf(acc, 0.f) + log1pf(__expf(-fabsf(acc)));
      float du = dl*u;
      #pragma unroll
      for (int n = 0; n < 16; n++){
        float e = __expf(dl*A[n]);
        P[n] *= e;
        Q[n] = Q[n]*e + du*sB[n][i];
      }
    }
  }
  size_t pbase = ((size_t)(bk*64 + s)*16)*192 + c;
  #pragma unroll
  for (int n = 0; n < 16; n++){ Pb[pbase + (size_t)n*192] = P[n]; Qb[pbase + (size_t)n*192] = Q[n]; }
}

// ------------------------------------------------ K12: scan phase B (hin in-place over Pb)
__global__ __launch_bounds__(256) void k_scanB(float* __restrict__ Pb,
    const float* __restrict__ Qb){
  int id = blockIdx.x*256 + threadIdx.x;
  int c = id % 192; int rest = id / 192; int n = rest % 16; int bk = rest / 16;
  float h = 0.f;
  for (int s = 0; s < 64; s++){
    size_t o = (((size_t)bk*64 + s)*16 + n)*192 + c;
    float P = Pb[o], Q = Qb[o];
    Pb[o] = h;
    h = P*h + Q;
  }
}

// ------------------------------------------------ K13a: scan phase C — non-atomic (fast-exp)
__global__ __launch_bounds__(192) void k_scanC_buf(const float* __restrict__ xsb,
    const float* __restrict__ dlsb, const float* __restrict__ Bsb, const float* __restrict__ Csb,
    const float* __restrict__ hinb, const float* __restrict__ dtw, const float* __restrict__ dtb,
    const float* __restrict__ alog, const float* __restrict__ Dsp, float* __restrict__ Y){
  int bid = blockIdx.x; int s = bid & 63; int k = (bid >> 6) & 3; int b = bid >> 8;
  int c = threadIdx.x; int bk = b*4 + k;
  __shared__ float sdl[384];
  __shared__ float sB[16][64];
  __shared__ float sC[16][64];
  size_t dbase = (size_t)(bk*64 + s)*384;
  for (int j = c; j < 384; j += 192) sdl[j] = dlsb[dbase + j];
  for (int j = c; j < 1024; j += 192){ int n = j >> 6, i = j & 63;
    size_t o = ((size_t)bk*16 + n)*4096 + (s << 6) + i;
    sB[n][i] = Bsb[o]; sC[n][i] = Csb[o]; }
  __syncthreads();
  float A[16], h[16];
  const float* arow = alog + ((size_t)k*192 + c)*16;
  bool fast = true;
  #pragma unroll
  for (int n = 0; n < 16; n++){
    A[n] = -__expf(arow[n]);
    if (fabsf(A[n] + (float)(n+1)) > 1e-3f) fast = false;
  }
  size_t hbase = ((size_t)(bk*64 + s)*16)*192 + c;
  #pragma unroll
  for (int n = 0; n < 16; n++) h[n] = hinb[hbase + (size_t)n*192];
  float dw[6];
  #pragma unroll
  for (int r = 0; r < 6; r++) dw[r] = dtw[((size_t)k*192 + c)*6 + r];
  float db = dtb[k*192 + c];
  float Dc = Dsp[k*192 + c];
  const float* xrow = xsb + ((size_t)bk*4096 + (s << 6))*192 + c;
  int p0, pst;
  if (k == 0){ p0 = s << 6;        pst = 1;  }
  else if (k == 1){ p0 = s;        pst = 64; }
  else if (k == 2){ p0 = 4095 - (s << 6); pst = -1; }
  else { p0 = 4095 - s;            pst = -64; }
  float* Yk = Y + (((size_t)k*4 + b)*4096)*192;
  if (fast){
    for (int i = 0; i < 64; i++){
      float u = xrow[(size_t)i*192];
      float acc = db;
      #pragma unroll
      for (int r = 0; r < 6; r++) acc += sdl[i*6 + r]*dw[r];
      float dl = fmaxf(acc, 0.f) + log1pf(__expf(-fabsf(acc)));
      float du = dl*u;
      float e1 = __expf(-dl), e = 1.f;
      float y = 0.f;
      #pragma unroll
      for (int n = 0; n < 16; n++){
        e *= e1;
        h[n] = h[n]*e + du*sB[n][i];
        y += h[n]*sC[n][i];
      }
      Yk[(size_t)(p0 + pst*i)*192 + c] = y + u*Dc;
    }
  } else {
    for (int i = 0; i < 64; i++){
      float u = xrow[(size_t)i*192];
      float acc = db;
      #pragma unroll
      for (int r = 0; r < 6; r++) acc += sdl[i*6 + r]*dw[r];
      float dl = fmaxf(acc, 0.f) + log1pf(__expf(-fabsf(acc)));
      float du = dl*u;
      float y = 0.f;
      #pragma unroll
      for (int n = 0; n < 16; n++){
        float e = __expf(dl*A[n]);
        h[n] = h[n]*e + du*sB[n][i];
        y += h[n]*sC[n][i];
      }
      Yk[(size_t)(p0 + pst*i)*192 + c] = y + u*Dc;
    }
  }
}

// ------------------------------------------------ K13b: scan phase C — atomic fallback (fast-exp)
__global__ __launch_bounds__(192) void k_scanC_atom(const float* __restrict__ xsb,
    const float* __restrict__ dlsb, const float* __restrict__ Bsb, const float* __restrict__ Csb,
    const float* __restrict__ hinb, const float* __restrict__ dtw, const float* __restrict__ dtb,
    const float* __restrict__ alog, const float* __restrict__ Dsp, float* __restrict__ yb){
  int bid = blockIdx.x; int s = bid & 63; int k = (bid >> 6) & 3; int b = bid >> 8;
  int c = threadIdx.x; int bk = b*4 + k;
  __shared__ float sdl[384];
  __shared__ float sB[16][64];
  __shared__ float sC[16][64];
  size_t dbase = (size_t)(bk*64 + s)*384;
  for (int j = c; j < 384; j += 192) sdl[j] = dlsb[dbase + j];
  for (int j = c; j < 1024; j += 192){ int n = j >> 6, i = j & 63;
    size_t o = ((size_t)bk*16 + n)*4096 + (s << 6) + i;
    sB[n][i] = Bsb[o]; sC[n][i] = Csb[o]; }
  __syncthreads();
  float A[16], h[16];
  const float* arow = alog + ((size_t)k*192 + c)*16;
  bool fast = true;
  #pragma unroll
  for (int n = 0; n < 16; n++){
    A[n] = -__expf(arow[n]);
    if (fabsf(A[n] + (float)(n+1)) > 1e-3f) fast = false;
  }
  size_t hbase = ((size_t)(bk*64 + s)*16)*192 + c;
  #pragma unroll
  for (int n = 0; n < 16; n++) h[n] = hinb[hbase + (size_t)n*192];
  float dw[6];
  #pragma unroll
  for (int r = 0; r < 6; r++) dw[r] = dtw[((size_t)k*192 + c)*6 + r];
  float db = dtb[k*192 + c];
  float Dc = Dsp[k*192 + c];
  const float* xrow = xsb + ((size_t)bk*4096 + (s << 6))*192 + c;
  int p0, pst;
  if (k == 0){ p0 = s << 6;        pst = 1;  }
  else if (k == 1){ p0 = s;        pst = 64; }
  else if (k == 2){ p0 = 4095 - (s << 6); pst = -1; }
  else { p0 = 4095 - s;            pst = -64; }
  for (int i = 0; i < 64; i++){
    float u = xrow[(size_t)i*192];
    float acc = db;
    #pragma unroll
    for (int r = 0; r < 6; r++) acc += sdl[i*6 + r]*dw[r];
    float dl = fmaxf(acc, 0.f) + log1pf(__expf(-fabsf(acc)));
    float du = dl*u;
    float y = 0.f;
    if (fast){
      float e1 = __expf(-dl), e = 1.f;
      #pragma unroll
      for (int n = 0; n < 16; n++){
        e *= e1;
        h[n] = h[n]*e + du*sB[n][i];
        y += h[n]*sC[n][i];
      }
    } else {
      #pragma unroll
      for (int n = 0; n < 16; n++){
        float e = __expf(dl*A[n]);
        h[n] = h[n]*e + du*sB[n][i];
        y += h[n]*sC[n][i];
      }
    }
    y += u*Dc;
    atomicAdd(&yb[((size_t)b*4096 + p0 + pst*i)*192 + c], y);
  }
}

// ------------------------------------------------ K14b: symmetry enhance (atomic path)
__global__ __launch_bounds__(256) void k_enh(const float* __restrict__ yb,
    const float* __restrict__ symw, float* __restrict__ yfb){
  int id = blockIdx.x*256 + threadIdx.x;
  int c = id % 192; int rest = id / 192; int l = rest & 4095; int b = rest >> 12;
  int w = l & 63; int lr = (l | 63) - w;
  float v  = yb[id];
  float vr = yb[(((size_t)b << 12) + lr)*192 + c];
  float wg = 1.f/(1.f + __expf(-symw[0]));
  float enh = v*(1.f - wg) + 0.5f*(v + vr)*wg;
  yfb[id] = v + 0.2f*enh;
}

// ------------------------------------------------ K15a (fused, bigws)
__global__ __launch_bounds__(256) void k_final_comb(const float* __restrict__ Y,
    const float* __restrict__ symw, const float* __restrict__ zT,
    const float* __restrict__ g, const float* __restrict__ bta,
    const float* __restrict__ opw, const float* __restrict__ x, float* __restrict__ out){
  int og = blockIdx.x & 1; int lt = (blockIdx.x >> 1) & 127; int b = blockIdx.x >> 8;
  int l0 = lt << 5;
  __shared__ float sv[32][193];
  __shared__ float wt[192*48];
  __shared__ float sg[192], sb2[192];
  __shared__ float smu[32], srs[32];
  int tid = threadIdx.x;
  const size_t S = (size_t)4096*192;
  float wg = 1.f/(1.f + __expf(-symw[0]));
  for (int idx = tid; idx < 6144; idx += 256){
    int r = idx/192, cc = idx - r*192;
    int l = l0 + r; int w = l & 63; int lr = (l | 63) - w;
    size_t base = (size_t)b*S + cc;
    size_t o1 = base + (size_t)l*192, o2 = base + (size_t)lr*192;
    float v  = Y[o1] + Y[4*S + o1] + Y[8*S + o1] + Y[12*S + o1];
    float vr = Y[o2] + Y[4*S + o2] + Y[8*S + o2] + Y[12*S + o2];
    float enh = v*(1.f - wg) + 0.5f*(v + vr)*wg;
    sv[r][cc] = v + 0.2f*enh;
  }
  if (tid < 192){ sg[tid] = g[tid]; sb2[tid] = bta[tid]; }
  int o0 = og*48;
  for (int idx = tid; idx < 9216; idx += 256){ int o = idx % 48, c = idx/48;
    wt[c*48 + o] = opw[(size_t)(o0 + o)*192 + c]; }
  __syncthreads();
  if (tid < 32){
    float s1 = 0.f, s2 = 0.f;
    for (int c = 0; c < 192; c++){ float v = sv[tid][c]; s1 += v; s2 += v*v; }
    float mu = s1*(1.0f/192.0f);
    smu[tid] = mu; srs[tid] = rsqrtf(s2*(1.0f/192.0f) - mu*mu + 1e-5f);
  }
  __syncthreads();
  for (int idx = tid; idx < 6144; idx += 256){ int l = idx & 31, c = idx >> 5;
    float zv = zT[((size_t)b*192 + c)*4096 + l0 + l];
    float v = sv[l][c];
    float yn = (v - smu[l])*srs[l]*sg[c] + sb2[c];
    sv[l][c] = yn * (zv/(1.f + __expf(-zv)));
  }
  __syncthreads();
  int l = tid & 31, grp = tid >> 5;
  float acc[6];
  #pragma unroll
  for (int j = 0; j < 6; j++) acc[j] = 0.f;
  for (int c = 0; c < 192; c++){
    float svv = sv[l][c];
    const float* wr = &wt[c*48 + grp*6];
    #pragma unroll
    for (int j = 0; j < 6; j += 2){
      float2 w2 = *(const float2*)&wr[j];
      acc[j]   += svv*w2.x; acc[j+1] += svv*w2.y;
    }
  }
  size_t ob = ((size_t)b*4096 + l0 + l)*96 + o0 + grp*6;
  #pragma unroll
  for (int j = 0; j < 6; j++) acc[j] += x[ob + j];
  #pragma unroll
  for (int j = 0; j < 6; j += 2){
    float2 v2; v2.x = acc[j]; v2.y = acc[j+1];
    *(float2*)&out[ob + j] = v2;
  }
}

// ------------------------------------------------ K15b: fallback
__global__ __launch_bounds__(256) void k_final(const float* __restrict__ yf,
    const float* __restrict__ zT, const float* __restrict__ g, const float* __restrict__ bta,
    const float* __restrict__ opw, const float* __restrict__ x, float* __restrict__ out){
  int og = blockIdx.x & 1; int lt = (blockIdx.x >> 1) & 127; int b = blockIdx.x >> 8;
  int l0 = lt << 5;
  __shared__ float sv[32][193];
  __shared__ float wt[192*48];
  __shared__ float sg[192], sb2[192];
  __shared__ float smu[32], srs[32];
  int tid = threadIdx.x;
  for (int idx = tid; idx < 6144; idx += 256){ int r = idx/192, c = idx - r*192;
    sv[r][c] = yf[((size_t)b*4096 + l0 + r)*192 + c]; }
  if (tid < 192){ sg[tid] = g[tid]; sb2[tid] = bta[tid]; }
  int o0 = og*48;
  for (int idx = tid; idx < 9216; idx += 256){ int o = idx % 48, c = idx/48;
    wt[c*48 + o] = opw[(size_t)(o0 + o)*192 + c]; }
  __syncthreads();
  if (tid < 32){
    float s1 = 0.f, s2 = 0.f;
    for (int c = 0; c < 192; c++){ float v = sv[tid][c]; s1 += v; s2 += v*v; }
    float mu = s1*(1.0f/192.0f);
    smu[tid] = mu; srs[tid] = rsqrtf(s2*(1.0f/192.0f) - mu*mu + 1e-5f);
  }
  __syncthreads();
  for (int idx = tid; idx < 6144; idx += 256){ int l = idx & 31, c = idx >> 5;
    float zv = zT[((size_t)b*192 + c)*4096 + l0 + l];
    float v = sv[l][c];
    float yn = (v - smu[l])*srs[l]*sg[c] + sb2[c];
    sv[l][c] = yn * (zv/(1.f + __expf(-zv)));
  }
  __syncthreads();
  int l = tid & 31, grp = tid >> 5;
  float acc[6];
  #pragma unroll
  for (int j = 0; j < 6; j++) acc[j] = 0.f;
  for (int c = 0; c < 192; c++){
    float svv = sv[l][c];
    const float* wr = &wt[c*48 + grp*6];
    #pragma unroll
    for (int j = 0; j < 6; j += 2){
      float2 w2 = *(const float2*)&wr[j];
      acc[j]   += svv*w2.x; acc[j+1] += svv*w2.y;
    }
  }
  size_t ob = ((size_t)b*4096 + l0 + l)*96 + o0 + grp*6;
  #pragma unroll
  for (int j = 0; j < 6; j++) acc[j] += x[ob + j];
  #pragma unroll
  for (int j = 0; j < 6; j += 2){
    float2 v2; v2.x = acc[j]; v2.y = acc[j+1];
    *(float2*)&out[ob + j] = v2;
  }
}

// ================================================================ host
extern "C" void kernel_launch(void* const* d_in, const int* in_sizes, int n_in,
                              void* d_out, int out_size, void* d_ws, size_t ws_size,
                              hipStream_t stream){
  (void)in_sizes; (void)n_in; (void)out_size;
  const float* ix   = (const float*)d_in[0];
  const float* ipw  = (const float*)d_in[1];
  const float* fw1  = (const float*)d_in[2];
  const float* fb1  = (const float*)d_in[3];
  const float* fw2  = (const float*)d_in[4];
  const float* fb2  = (const float*)d_in[5];
  const float* ww   = (const float*)d_in[6];
  const float* wb   = (const float*)d_in[7];
  const float* dww  = (const float*)d_in[8];
  const float* dwb  = (const float*)d_in[9];
  const float* symw = (const float*)d_in[10];
  const float* xpw  = (const float*)d_in[11];
  const float* dtw  = (const float*)d_in[12];
  const float* dtb  = (const float*)d_in[13];
  const float* alog = (const float*)d_in[14];
  const float* Dsp  = (const float*)d_in[15];
  const float* ong  = (const float*)d_in[16];
  const float* onb  = (const float*)d_in[17];
  const float* opw  = (const float*)d_in[18];
  const float* rmsw = (const float*)d_in[19];

  float* W = (float*)d_ws;
  const size_t SZ_BLC = 3145728, SZ_F = 1622016, SZ_H = 786432;
  float* zT  = W;
  float* ab  = zT + SZ_BLC;
  float* R0  = ab + SZ_BLC;
  // phase 1
  float* xc    = R0;
  float* fre   = xc  + SZ_BLC;
  float* fim   = fre + SZ_F;
  float* fab   = fim + SZ_F;
  float* mb    = fab + SZ_F;
  float* llb   = mb  + SZ_F;
  float* lhb   = llb + SZ_H;                 // lh,hl,hh = 3*SZ_H fp32
  float* wnew  = lhb + 3*SZ_H;               // 2,359,296 fp32 (full-K conv out)
  unsigned short* wqb2 = (unsigned short*)(wnew + 2359296);   // 331,776 bf16
  // phase 2
  float* Bsb  = R0;
  float* Csb  = Bsb + 1048576;
  float* dlsb = Csb + 1048576;
  float* xsb  = dlsb + 393216;
  float* Pb   = xsb + 12582912;
  float* aT   = Pb;
  float* Qb   = Pb + SZ_BLC;
  float* Yb   = Qb;
  float* ybA  = Qb + SZ_BLC;
  float* yfb  = xsb;

  const size_t NEED_BIG = (size_t)(6291456 + 30801920) * 4;
  bool bigws = (ws_size >= NEED_BIG);

  hipLaunchKernelGGL(k_rms_inproj, dim3(2048),   dim3(256), 0, stream, ix, rmsw, ipw, xc, zT);
  hipLaunchKernelGGL(k_dft_fwd,    dim3(4*192),  dim3(256), 0, stream, xc, fre, fim, fab,
                     llb, lhb, lhb + SZ_H, lhb + 2*SZ_H);
  hipLaunchKernelGGL(k_cvt_w,      dim3(1296),   dim3(256), 0, stream, ww, wqb2);
  hipLaunchKernelGGL(k_cmix1,      dim3(864),    dim3(256), 0, stream, fab, fw1, fb1, mb);
  hipLaunchKernelGGL(k_cmix2,      dim3(864),    dim3(256), 0, stream, mb, fw2, fb2, fre, fim, fab);
  hipLaunchKernelGGL(k_wconv_mfma, dim3(576),    dim3(256), 0, stream, lhb, wqb2, wnew);
  hipLaunchKernelGGL(k_ifwd,       dim3(768),    dim3(256), 0, stream, fre, fim, xc, llb, wnew, wb, dww, dwb, ab, aT);
  hipLaunchKernelGGL(k_xproj,      dim3(1024),   dim3(256), 0, stream, ab, aT, xpw, Bsb, Csb, dlsb, xsb);
  hipLaunchKernelGGL(k_scanA,      dim3(1024),   dim3(192), 0, stream, xsb, dlsb, Bsb, dtw, dtb, alog, Pb, Qb);
  hipLaunchKernelGGL(k_scanB,      dim3(192),    dim3(256), 0, stream, Pb, Qb);
  if (bigws){
    hipLaunchKernelGGL(k_scanC_buf,  dim3(1024), dim3(192), 0, stream, xsb, dlsb, Bsb, Csb, Pb, dtw, dtb, alog, Dsp, Yb);
    hipLaunchKernelGGL(k_final_comb, dim3(1024), dim3(256), 0, stream, Yb, symw, zT, ong, onb, opw, ix, (float*)d_out);
  } else {
    hipLaunchKernelGGL(k_zero,       dim3(12288), dim3(256), 0, stream, ybA, (int)SZ_BLC);
    hipLaunchKernelGGL(k_scanC_atom, dim3(1024),  dim3(192), 0, stream, xsb, dlsb, Bsb, Csb, Pb, dtw, dtb, alog, Dsp, ybA);
    hipLaunchKernelGGL(k_enh,        dim3(12288), dim3(256), 0, stream, ybA, symw, yfb);
    hipLaunchKernelGGL(k_final,      dim3(1024),  dim3(256), 0, stream, yfb, zT, ong, onb, opw, ix, (float*)d_out);
  }
}

// Round 14
// 689.272 us; speedup vs baseline: 1.2067x; 1.1100x over previous
//
#include <hip/hip_runtime.h>
#include <hip/hip_bf16.h>

#define CI 192
#define LL_ 4096

typedef __bf16 v8bf __attribute__((ext_vector_type(8)));
typedef float  v4f  __attribute__((ext_vector_type(4)));
typedef unsigned short v8us __attribute__((ext_vector_type(8)));

__device__ __forceinline__ unsigned short f2bf(float v){
  unsigned int u = __float_as_uint(v);
  return (unsigned short)((u + 0x7FFFu + ((u >> 16) & 1u)) >> 16);
}

__global__ __launch_bounds__(256) void k_zero(float* __restrict__ p, int n){
  int i = blockIdx.x*256 + threadIdx.x;
  if (i < n) p[i] = 0.f;
}

// ------------------------------------------------ K1: RMSNorm + in_proj (tiled GEMM, 48-o tiles)
__global__ __launch_bounds__(256) void k_rms_inproj(const float* __restrict__ x,
    const float* __restrict__ rmsw, const float* __restrict__ ipw,
    float* __restrict__ xc, float* __restrict__ zT){
  int og = blockIdx.x & 7; int lt = (blockIdx.x >> 3) & 63; int b = blockIdx.x >> 9;
  int l0 = lt << 6;
  __shared__ float xt[64][97];
  __shared__ float wt[96*48];
  __shared__ float rr[64];
  __shared__ float rw[96];
  int tid = threadIdx.x;
  for (int idx = tid; idx < 6144; idx += 256){ int r = idx/96, d = idx - r*96;
    xt[r][d] = x[((size_t)b*4096 + l0 + r)*96 + d]; }
  if (tid < 96) rw[tid] = rmsw[tid];
  int o0 = og*48;
  for (int idx = tid; idx < 4608; idx += 256){ int o = idx%48, d = idx/48;
    wt[d*48 + o] = ipw[(size_t)(o0 + o)*96 + d]; }
  __syncthreads();
  if (tid < 64){
    float s = 0.f;
    for (int d = 0; d < 96; d++){ float v = xt[tid][d]; s += v*v; }
    rr[tid] = rsqrtf(s*(1.0f/96.0f) + 1e-5f);
  }
  __syncthreads();
  for (int idx = tid; idx < 6144; idx += 256){ int r = idx/96, d = idx - r*96;
    xt[r][d] *= rr[r]*rw[d]; }
  __syncthreads();
  int l = tid & 63, grp = tid >> 6;
  float acc[12];
  #pragma unroll
  for (int j = 0; j < 12; j++) acc[j] = 0.f;
  for (int d = 0; d < 96; d++){
    float xv = xt[l][d];
    const float* wr = &wt[d*48 + grp*12];
    #pragma unroll
    for (int j = 0; j < 12; j += 4){
      float4 w4 = *(const float4*)&wr[j];
      acc[j]   += xv*w4.x; acc[j+1] += xv*w4.y;
      acc[j+2] += xv*w4.z; acc[j+3] += xv*w4.w;
    }
  }
  #pragma unroll
  for (int j = 0; j < 12; j++){
    int o = o0 + grp*12 + j;
    if (o < 192) xc[((size_t)b*192 + o)*4096 + l0 + l] = acc[j];
    else         zT[((size_t)b*192 + (o-192))*4096 + l0 + l] = acc[j];
  }
}

// ------------------------------------------------ K2: forward rfft2 (ortho) + fused Haar DWT
__global__ __launch_bounds__(256) void k_dft_fwd(const float* __restrict__ xc,
    float* __restrict__ fre, float* __restrict__ fim, float* __restrict__ fab,
    float* __restrict__ ll, float* __restrict__ lh, float* __restrict__ hl, float* __restrict__ hh){
  int plane = blockIdx.x;
  __shared__ float sxT[64*65];
  __shared__ float t1r[64*34], t1i[64*34];
  __shared__ float tabr[16], tabi[16];
  __shared__ float ct64[64], st64[64];
  int tid = threadIdx.x;
  const float* X = xc + (size_t)plane*4096;
  for (int i = tid; i < 4096; i += 256){ int h = i >> 6, w = i & 63; sxT[w*65 + h] = X[i]; }
  if (tid < 16){ tabr[tid] = cospif((float)tid/8.0f); tabi[tid] = -sinpif((float)tid/8.0f); }
  if (tid < 64){ ct64[tid] = cospif((float)tid/32.0f); st64[tid] = sinpif((float)tid/32.0f); }
  __syncthreads();
  {
    size_t qbase = (size_t)plane*1024;
    for (int idx = tid; idx < 1024; idx += 256){
      int y2 = idx >> 5, x2 = idx & 31;
      float a_ = sxT[(2*x2)*65 + 2*y2],     b_ = sxT[(2*x2+1)*65 + 2*y2];
      float c_ = sxT[(2*x2)*65 + 2*y2+1],   d_ = sxT[(2*x2+1)*65 + 2*y2+1];
      ll[qbase + idx] = (a_+b_+c_+d_)*0.5f; lh[qbase + idx] = (a_-b_+c_-d_)*0.5f;
      hl[qbase + idx] = (a_+b_-c_-d_)*0.5f; hh[qbase + idx] = (a_-b_-c_+d_)*0.5f;
    }
  }
  {
    int hp = tid & 31, g = tid >> 5;
    float a0r[4], a0i[4], a1r[4], a1i[4];
    #pragma unroll
    for (int j = 0; j < 4; j++){ a0r[j]=0.f; a0i[j]=0.f; a1r[j]=0.f; a1i[j]=0.f; }
    float s32_0 = 0.f, s32_1 = 0.f;
    for (int w = 0; w < 64; w++){
      float xv0 = sxT[w*65 + hp];
      float xv1 = sxT[w*65 + hp + 32];
      int m0 = (w*g) & 15;
      float twr = tabr[m0], twi = tabi[m0];
      int ms = w & 15;
      float str = tabr[ms], sti = tabi[ms];
      #pragma unroll
      for (int j = 0; j < 4; j++){
        a0r[j] += xv0*twr; a0i[j] += xv0*twi;
        a1r[j] += xv1*twr; a1i[j] += xv1*twi;
        float nr = twr*str - twi*sti;
        float ni = twr*sti + twi*str;
        twr = nr; twi = ni;
      }
      if (g == 0){ float sg = (w & 1) ? -1.f : 1.f; s32_0 += xv0*sg; s32_1 += xv1*sg; }
    }
    #pragma unroll
    for (int j = 0; j < 4; j++){
      int k = 4*g + j;
      t1r[hp*34 + k] = a0r[j];        t1i[hp*34 + k] = a0i[j];
      t1r[(hp+32)*34 + k] = a1r[j];   t1i[(hp+32)*34 + k] = a1i[j];
    }
    if (g == 0){
      t1r[hp*34 + 32] = s32_0;      t1i[hp*34 + 32] = 0.f;
      t1r[(hp+32)*34 + 32] = s32_1; t1i[(hp+32)*34 + 32] = 0.f;
    }
  }
  __syncthreads();
  {
    int fp = tid & 31, g = tid >> 5;
    float stepr = cospif((float)fp/32.0f), stepi = -sinpif((float)fp/32.0f);
    float a0r[4], a0i[4], a1r[4], a1i[4];
    #pragma unroll
    for (int j = 0; j < 4; j++){ a0r[j]=0.f; a0i[j]=0.f; a1r[j]=0.f; a1i[j]=0.f; }
    float b0r=0.f, b0i=0.f, b1r=0.f, b1i=0.f;
    for (int hb = 0; hb < 4; hb++){
      int m = ((hb*16)*fp) & 63;
      float twr = ct64[m], twi = -st64[m];
      for (int hh2 = 0; hh2 < 16; hh2++){
        int h = hb*16 + hh2;
        float sg = (h & 1) ? -1.f : 1.f;
        #pragma unroll
        for (int j = 0; j < 4; j++){
          float Tr = t1r[h*34 + 4*g + j], Ti = t1i[h*34 + 4*g + j];
          float pr = Tr*twr - Ti*twi;
          float pi = Tr*twi + Ti*twr;
          a0r[j] += pr; a0i[j] += pi;
          a1r[j] += sg*pr; a1i[j] += sg*pi;
        }
        if (g == 0){
          float Tr = t1r[h*34 + 32], Ti = t1i[h*34 + 32];
          float pr = Tr*twr - Ti*twi, pi = Tr*twi + Ti*twr;
          b0r += pr; b0i += pi; b1r += sg*pr; b1i += sg*pi;
        }
        float nr = twr*stepr - twi*stepi, ni = twr*stepi + twi*stepr;
        twr = nr; twi = ni;
      }
    }
    size_t base = (size_t)plane*2112;
    #pragma unroll
    for (int j = 0; j < 4; j++){
      int k = 4*g + j;
      float r0 = a0r[j]*(1.f/64.f), i0 = a0i[j]*(1.f/64.f);
      float r1 = a1r[j]*(1.f/64.f), i1 = a1i[j]*(1.f/64.f);
      fre[base + fp*33 + k] = r0; fim[base + fp*33 + k] = i0;
      fab[base + fp*33 + k] = sqrtf(r0*r0 + i0*i0);
      fre[base + (fp+32)*33 + k] = r1; fim[base + (fp+32)*33 + k] = i1;
      fab[base + (fp+32)*33 + k] = sqrtf(r1*r1 + i1*i1);
    }
    if (g == 0){
      float r0 = b0r*(1.f/64.f), i0 = b0i*(1.f/64.f);
      float r1 = b1r*(1.f/64.f), i1 = b1i*(1.f/64.f);
      fre[base + fp*33 + 32] = r0; fim[base + fp*33 + 32] = i0;
      fab[base + fp*33 + 32] = sqrtf(r0*r0 + i0*i0);
      fre[base + (fp+32)*33 + 32] = r1; fim[base + (fp+32)*33 + 32] = i1;
      fab[base + (fp+32)*33 + 32] = sqrtf(r1*r1 + i1*i1);
    }
  }
}

// ------------------------------------------------ K3: m = gelu(W1 @ |xf| + b1)  (LDS weights)
__global__ __launch_bounds__(256) void k_cmix1(const float* __restrict__ fab,
    const float* __restrict__ w1, const float* __restrict__ b1, float* __restrict__ m){
  int bid = blockIdx.x;
  int pt = bid % 9; int og = (bid/9) % 24; int b = bid/216;
  int tid = threadIdx.x;
  int p = pt*256 + tid; bool act = p < 2112;
  __shared__ float wl[192*8];
  for (int idx = tid; idx < 1536; idx += 256){ int o = idx & 7, c = idx >> 3;
    wl[c*8 + o] = w1[(size_t)(og*8 + o)*192 + c]; }
  __syncthreads();
  float acc[8];
  #pragma unroll
  for (int o = 0; o < 8; o++) acc[o] = b1[og*8 + o];
  const float* xb = fab + (size_t)b*CI*2112 + p;
  for (int c = 0; c < 192; c++){
    float xv = act ? xb[(size_t)c*2112] : 0.f;
    float4 wa = *(const float4*)&wl[c*8];
    float4 wb4 = *(const float4*)&wl[c*8 + 4];
    acc[0] += xv*wa.x;  acc[1] += xv*wa.y;  acc[2] += xv*wa.z;  acc[3] += xv*wa.w;
    acc[4] += xv*wb4.x; acc[5] += xv*wb4.y; acc[6] += xv*wb4.z; acc[7] += xv*wb4.w;
  }
  if (act){
    #pragma unroll
    for (int o = 0; o < 8; o++){
      float a = acc[o];
      m[((size_t)b*192 + og*8 + o)*2112 + p] = 0.5f*a*(1.0f + erff(a*0.70710678118654752f));
    }
  }
}

// ------------------------------------------------ K4: mag = W2 @ m + b2; in-place (LDS weights)
__global__ __launch_bounds__(256) void k_cmix2(const float* __restrict__ m,
    const float* __restrict__ w2, const float* __restrict__ bi2,
    float* __restrict__ fre, float* __restrict__ fim, const float* __restrict__ fab){
  int bid = blockIdx.x;
  int pt = bid % 9; int og = (bid/9) % 24; int b = bid/216;
  int tid = threadIdx.x;
  int p = pt*256 + tid; bool act = p < 2112;
  __shared__ float wl[192*8];
  for (int idx = tid; idx < 1536; idx += 256){ int o = idx & 7, c = idx >> 3;
    wl[c*8 + o] = w2[(size_t)(og*8 + o)*192 + c]; }
  __syncthreads();
  float acc[8];
  #pragma unroll
  for (int o = 0; o < 8; o++) acc[o] = bi2[og*8 + o];
  const float* xb = m + (size_t)b*CI*2112 + p;
  for (int c = 0; c < 192; c++){
    float xv = act ? xb[(size_t)c*2112] : 0.f;
    float4 wa = *(const float4*)&wl[c*8];
    float4 wb4 = *(const float4*)&wl[c*8 + 4];
    acc[0] += xv*wa.x;  acc[1] += xv*wa.y;  acc[2] += xv*wa.z;  acc[3] += xv*wa.w;
    acc[4] += xv*wb4.x; acc[5] += xv*wb4.y; acc[6] += xv*wb4.z; acc[7] += xv*wb4.w;
  }
  if (act){
    #pragma unroll
    for (int o = 0; o < 8; o++){
      size_t id = ((size_t)b*192 + og*8 + o)*2112 + p;
      float ab = fab[id];
      float re, im;
      if (ab > 1e-30f){ float sc = acc[o]/ab; re = sc*fre[id]; im = sc*fim[id]; }
      else { re = acc[o]; im = 0.f; }
      fre[id] = re; fim[id] = im;
    }
  }
}

// ------------------------------------------------ K5b: convert weights -> bf16 [q][oc][ic]
__global__ __launch_bounds__(256) void k_cvt_w(const float* __restrict__ ww,
    unsigned short* __restrict__ wqb2){
  int idx = blockIdx.x*256 + threadIdx.x;
  if (idx >= 331776) return;
  int ic = idx % 192; int rest = idx / 192;
  int oc = rest % 192; int q = rest / 192;
  wqb2[idx] = f2bf(ww[((size_t)oc*192 + ic)*9 + q]);
}

// ------------------------------------------------ K6: 3x3 full conv via bf16 MFMA, A staged once
__global__ __launch_bounds__(256) void k_wconv_mfma(const float* __restrict__ lhb,
    const unsigned short* __restrict__ wqb2, float* __restrict__ wnew){
  int bid = blockIdx.x;
  int nt = bid % 3; int mt = (bid/3) & 15; int img = bid/48;
  int o0 = nt*64;
  __shared__ __align__(16) unsigned short sm_us[40000];  // 80 KB
  unsigned short* Aband = sm_us;            // [4 row][34 col] x stride 200
  unsigned short* Bbuf  = sm_us + 27200;    // [64 oc] x stride 200
  float* T = (float*)sm_us;                 // epilogue [64 m][65]
  int tid = threadIdx.x;
  int lane = tid & 63, wv = tid >> 6;
  int quad = lane >> 4, n16 = lane & 15;
  const float* base = lhb + (size_t)img*196608;
  for (int idx = tid; idx < 26112; idx += 256){
    int pix = idx % 136;
    int ic  = idx / 136;
    int r = pix / 34, col = pix - r*34;
    int gr = 2*mt - 1 + r, gc = col - 1;
    float v = (gr >= 0 && gr < 32 && gc >= 0 && gc < 32) ? base[(size_t)ic*1024 + gr*32 + gc] : 0.f;
    Aband[pix*200 + ic] = f2bf(v);
  }
  v4f acc[4];
  #pragma unroll
  for (int t2 = 0; t2 < 4; t2++) acc[t2] = (v4f){0.f,0.f,0.f,0.f};
  for (int q = 0; q < 9; q++){
    int ky = q/3, kx = q - ky*3;
    if (q) __syncthreads();
    for (int idx = tid; idx < 1536; idx += 256){
      int oc = idx / 24, g = idx - (idx/24)*24;
      v8us wv8 = *(const v8us*)&wqb2[((size_t)(q*192) + o0 + oc)*192 + g*8];
      *(v8us*)&Bbuf[oc*200 + g*8] = wv8;
    }
    __syncthreads();
    #pragma unroll
    for (int icc = 0; icc < 6; icc++){
      int c0 = icc*32;
      v8us bu = *(const v8us*)&Bbuf[(16*wv + n16)*200 + c0 + quad*8];
      v8bf bv = __builtin_bit_cast(v8bf, bu);
      #pragma unroll
      for (int t2 = 0; t2 < 4; t2++){
        int mm = t2*16 + n16;
        int pix = ((mm >> 5) + ky)*34 + (mm & 31) + kx;
        v8us au = *(const v8us*)&Aband[pix*200 + c0 + quad*8];
        v8bf av = __builtin_bit_cast(v8bf, au);
        acc[t2] = __builtin_amdgcn_mfma_f32_16x16x32_bf16(av, bv, acc[t2], 0, 0, 0);
      }
    }
  }
  __syncthreads();
  #pragma unroll
  for (int t2 = 0; t2 < 4; t2++)
    #pragma unroll
    for (int r = 0; r < 4; r++)
      T[(16*t2 + quad*4 + r)*65 + 16*wv + n16] = acc[t2][r];
  __syncthreads();
  float* outb = wnew + (size_t)img*196608;
  for (int idx = tid; idx < 4096; idx += 256){
    int mm = idx & 63, oc = idx >> 6;
    outb[(size_t)(o0 + oc)*1024 + mt*64 + mm] = T[mm*65 + oc];
  }
}

// ------------------------------------------------ K7 (fused): irfft2 + combine + depthwise3x3 + SiLU -> ab, aT
__global__ __launch_bounds__(256) void k_ifwd(const float* __restrict__ fre2,
    const float* __restrict__ fim2, const float* __restrict__ xc,
    const float* __restrict__ ll, const float* __restrict__ wnew, const float* __restrict__ wb,
    const float* __restrict__ dww, const float* __restrict__ dwb,
    float* __restrict__ ab, float* __restrict__ aT){
  int plane = blockIdx.x;
  int c = plane % 192;
  __shared__ float sm[12936];
  float* gr  = sm;
  float* gi  = sm + 2176;
  float* ur  = sm + 4352;
  float* ui  = sm + 6528;
  float* sx2 = sm + 8704;
  float* t64r = sm + 12800; float* t64i = sm + 12864;
  float* t4r  = sm + 12928; float* t4i  = sm + 12932;
  float* scratch = sm;
  int tid = threadIdx.x;
  for (int i = tid; i < 2112; i += 256){
    size_t o = (size_t)plane*2112 + i;
    int f = i/33, k = i - f*33;
    gr[f*34 + k] = fre2[o]; gi[f*34 + k] = fim2[o];
  }
  if (tid < 64){ t64r[tid] = cospif((float)tid/32.0f); t64i[tid] = sinpif((float)tid/32.0f); }
  if (tid < 4){ t4r[tid] = (tid == 0) ? 1.f : ((tid == 2) ? -1.f : 0.f);
                t4i[tid] = (tid == 1) ? 1.f : ((tid == 3) ? -1.f : 0.f); }
  __syncthreads();
  {
    int hp = tid & 31, g = tid >> 5;
    float stepr = cospif((float)hp/32.0f), stepi = sinpif((float)hp/32.0f);
    float a0r[4], a0i[4], a1r[4], a1i[4];
    #pragma unroll
    for (int j = 0; j < 4; j++){ a0r[j]=0.f; a0i[j]=0.f; a1r[j]=0.f; a1i[j]=0.f; }
    float b0r=0.f, b0i=0.f, b1r=0.f, b1i=0.f;
    for (int fb = 0; fb < 4; fb++){
      int m = ((fb*16)*hp) & 63;
      float twr = t64r[m], twi = t64i[m];
      for (int ff = 0; ff < 16; ff++){
        int f = fb*16 + ff;
        float sg = (f & 1) ? -1.f : 1.f;
        #pragma unroll
        for (int j = 0; j < 4; j++){
          float Gr = gr[f*34 + 4*g + j], Gi = gi[f*34 + 4*g + j];
          float pr = Gr*twr - Gi*twi;
          float pi = Gr*twi + Gi*twr;
          a0r[j] += pr; a0i[j] += pi;
          a1r[j] += sg*pr; a1i[j] += sg*pi;
        }
        if (g == 0){
          float Gr = gr[f*34 + 32], Gi = gi[f*34 + 32];
          float pr = Gr*twr - Gi*twi, pi = Gr*twi + Gi*twr;
          b0r += pr; b0i += pi; b1r += sg*pr; b1i += sg*pi;
        }
        float nr = twr*stepr - twi*stepi, ni = twr*stepi + twi*stepr;
        twr = nr; twi = ni;
      }
    }
    __syncthreads();
    #pragma unroll
    for (int j = 0; j < 4; j++){
      int k = 4*g + j;
      float ck = (k == 0) ? (1.f/64.f) : (2.f/64.f);
      ur[hp*34 + k] = a0r[j]*ck;       ui[hp*34 + k] = a0i[j]*ck;
      ur[(hp+32)*34 + k] = a1r[j]*ck;  ui[(hp+32)*34 + k] = a1i[j]*ck;
    }
    if (g == 0){
      ur[hp*34 + 32] = b0r*(1.f/64.f);      ui[hp*34 + 32] = b0i*(1.f/64.f);
      ur[(hp+32)*34 + 32] = b1r*(1.f/64.f); ui[(hp+32)*34 + 32] = b1i*(1.f/64.f);
    }
  }
  __syncthreads();
  {
    int h = tid & 63, wg = tid >> 6;
    float acc[16];
    #pragma unroll
    for (int j = 0; j < 16; j++) acc[j] = 0.f;
    for (int k = 0; k <= 32; k++){
      float Ur = ur[h*34 + k], Ui = ui[h*34 + k];
      int m = (k*wg) & 3;
      float twr = t4r[m], twi = t4i[m];
      float str = t64r[k], sti = t64i[k];
      #pragma unroll
      for (int j = 0; j < 16; j++){
        acc[j] += Ur*twr - Ui*twi;
        float nr = twr*str - twi*sti, ni = twr*sti + twi*str;
        twr = nr; twi = ni;
      }
    }
    #pragma unroll
    for (int j = 0; j < 16; j++) sx2[h*64 + 16*wg + j] = acc[j];
  }
  __syncthreads();
  float bia = wb[c];
  for (int p = tid; p < 4096; p += 256){
    int h = p >> 6, w = p & 63;
    size_t q = (size_t)plane*1024 + (size_t)(h >> 1)*32 + (w >> 1);
    float LLv = ll[q];
    float LH = wnew[q] + bia;
    float HL = wnew[786432 + q] + bia;
    float HH = wnew[1572864 + q] + bia;
    float v;
    bool hb = (h & 1), wbit = (w & 1);
    if (!hb && !wbit)      v = (LLv + LH + HL + HH)*0.5f;
    else if (!hb && wbit)  v = (LLv - LH + HL - HH)*0.5f;
    else if (hb && !wbit)  v = (LLv + LH - HL - HH)*0.5f;
    else                   v = (LLv - LH - HL + HH)*0.5f;
    sx2[p] = 2.0f*xc[(size_t)plane*4096 + p] + sx2[p] + v;
  }
  __syncthreads();
  float wk[9];
  #pragma unroll
  for (int q = 0; q < 9; q++) wk[q] = dww[c*9 + q];
  float dbv = dwb[c];
  for (int p = tid; p < 4096; p += 256){
    int h = p >> 6, w = p & 63;
    float acc = dbv;
    #pragma unroll
    for (int ky = 0; ky < 3; ky++){
      int yy = h + ky - 1; if (yy < 0 || yy > 63) continue;
      #pragma unroll
      for (int kx = 0; kx < 3; kx++){
        int xx = w + kx - 1; if (xx < 0 || xx > 63) continue;
        acc += sx2[yy*64 + xx]*wk[ky*3 + kx];
      }
    }
    scratch[h*65 + w] = acc / (1.f + __expf(-acc));
  }
  __syncthreads();
  float* abp = ab + (size_t)plane*4096;
  float* aTp = aT + (size_t)plane*4096;
  for (int p = tid; p < 4096; p += 256){
    abp[p] = scratch[(p >> 6)*65 + (p & 63)];
    aTp[p] = scratch[(p & 63)*65 + (p >> 6)];
  }
}

// ------------------------------------------------ K10: x_proj; wave-split GEMM
__global__ __launch_bounds__(256) void k_xproj(const float* __restrict__ ab,
    const float* __restrict__ aT, const float* __restrict__ xpw,
    float* __restrict__ Bsb, float* __restrict__ Csb, float* __restrict__ dlsb,
    float* __restrict__ xsb){
  int bid = blockIdx.x;
  int s = bid & 63; int k = (bid >> 6) & 3; int b = bid >> 8;
  int tid = threadIdx.x;
  __shared__ float als[192][65];
  __shared__ float dls[6][64];
  int l0 = s << 6;
  const float* src = (k & 1) ? aT : ab;
  int off0 = (k < 2) ? l0 : (4095 - l0);
  int stp  = (k < 2) ? 1 : -1;
  for (int idx = tid; idx < 192*64; idx += 256){
    int d = idx >> 6, i = idx & 63;
    als[d][i] = src[((size_t)b*192 + d)*4096 + off0 + stp*i];
  }
  __syncthreads();
  {
    int i = tid & 63, wg = tid >> 6;
    const float* wr[10];
    #pragma unroll
    for (int r = 0; r < 10; r++){
      int cp = wg + 4*r; if (cp > 37) cp = 37;
      wr[r] = xpw + ((size_t)k*38 + cp)*192;
    }
    float acc[10];
    #pragma unroll
    for (int r = 0; r < 10; r++) acc[r] = 0.f;
    for (int d = 0; d < 192; d++){
      float v = als[d][i];
      #pragma unroll
      for (int r = 0; r < 10; r++) acc[r] += v*wr[r][d];
    }
    #pragma unroll
    for (int r = 0; r < 10; r++){
      int cp = wg + 4*r;
      if (cp > 37) continue;
      if (cp < 6) dls[cp][i] = acc[r];
      else if (cp < 22) Bsb[((size_t)(b*4 + k)*16 + (cp - 6 ))*4096 + l0 + i] = acc[r];
      else              Csb[((size_t)(b*4 + k)*16 + (cp - 22))*4096 + l0 + i] = acc[r];
    }
  }
  size_t xbase = ((size_t)(b*4 + k)*4096 + l0)*192;
  for (int j = tid; j < 192*64; j += 256){
    int i = j / 192, c = j % 192;
    xsb[xbase + (size_t)i*192 + c] = als[c][i];
  }
  __syncthreads();
  size_t dbase = (size_t)((b*4 + k)*64 + s)*384;
  for (int j = tid; j < 384; j += 256){
    int i = j/6, r = j - i*6;
    dlsb[dbase + j] = dls[r][i];
  }
}

// ------------------------------------------------ K11: scan phase A (fast-exp, cheap softplus)
__global__ __launch_bounds__(192) void k_scanA(const float* __restrict__ xsb,
    const float* __restrict__ dlsb, const float* __restrict__ Bsb,
    const float* __restrict__ dtw, const float* __restrict__ dtb,
    const float* __restrict__ alog, float* __restrict__ Pb, float* __restrict__ Qb){
  int bid = blockIdx.x; int s = bid & 63; int k = (bid >> 6) & 3; int b = bid >> 8;
  int c = threadIdx.x; int bk = b*4 + k;
  __shared__ float sdl[384];
  __shared__ float sB[16][64];
  size_t dbase = (size_t)(bk*64 + s)*384;
  for (int j = c; j < 384; j += 192) sdl[j] = dlsb[dbase + j];
  for (int j = c; j < 1024; j += 192){ int n = j >> 6, i = j & 63;
    sB[n][i] = Bsb[((size_t)bk*16 + n)*4096 + (s << 6) + i]; }
  __syncthreads();
  float A[16], P[16], Q[16];
  const float* arow = alog + ((size_t)k*192 + c)*16;
  bool fast = true;
  #pragma unroll
  for (int n = 0; n < 16; n++){
    A[n] = -__expf(arow[n]); P[n] = 1.f; Q[n] = 0.f;
    if (fabsf(A[n] + (float)(n+1)) > 1e-3f) fast = false;
  }
  float dw[6];
  #pragma unroll
  for (int r = 0; r < 6; r++) dw[r] = dtw[((size_t)k*192 + c)*6 + r];
  float db = dtb[k*192 + c];
  const float* xrow = xsb + ((size_t)bk*4096 + (s << 6))*192 + c;
  if (fast){
    for (int i = 0; i < 64; i++){
      float u = xrow[(size_t)i*192];
      float acc = db;
      #pragma unroll
      for (int r = 0; r < 6; r++) acc += sdl[i*6 + r]*dw[r];
      float ec = __expf(fminf(acc, 80.f));
      float dl = __logf(1.f + ec);
      float e1 = __builtin_amdgcn_rcpf(1.f + ec);
      float du = dl*u;
      float e = 1.f;
      #pragma unroll
      for (int n = 0; n < 16; n++){
        e *= e1;
        P[n] *= e;
        Q[n] = Q[n]*e + du*sB[n][i];
      }
    }
  } else {
    for (int i = 0; i < 64; i++){
      float u = xrow[(size_t)i*192];
      float acc = db;
      #pragma unroll
      for (int r = 0; r < 6; r++) acc += sdl[i*6 + r]*dw[r];
      float ec = __expf(fminf(acc, 80.f));
      float dl = __logf(1.f + ec);
      float du = dl*u;
      #pragma unroll
      for (int n = 0; n < 16; n++){
        float e = __expf(dl*A[n]);
        P[n] *= e;
        Q[n] = Q[n]*e + du*sB[n][i];
      }
    }
  }
  size_t pbase = ((size_t)(bk*64 + s)*16)*192 + c;
  #pragma unroll
  for (int n = 0; n < 16; n++){ Pb[pbase + (size_t)n*192] = P[n]; Qb[pbase + (size_t)n*192] = Q[n]; }
}

// ------------------------------------------------ K12: scan phase B (hin in-place over Pb)
__global__ __launch_bounds__(256) void k_scanB(float* __restrict__ Pb,
    const float* __restrict__ Qb){
  int id = blockIdx.x*256 + threadIdx.x;
  int c = id % 192; int rest = id / 192; int n = rest % 16; int bk = rest / 16;
  float h = 0.f;
  for (int s = 0; s < 64; s++){
    size_t o = (((size_t)bk*64 + s)*16 + n)*192 + c;
    float P = Pb[o], Q = Qb[o];
    Pb[o] = h;
    h = P*h + Q;
  }
}

// ------------------------------------------------ K13a: scan phase C — non-atomic, scan-order Y writes
// Y layout: [bk][iscan][c] (fully sequential streaming per block)
__global__ __launch_bounds__(192) void k_scanC_buf(const float* __restrict__ xsb,
    const float* __restrict__ dlsb, const float* __restrict__ Bsb, const float* __restrict__ Csb,
    const float* __restrict__ hinb, const float* __restrict__ dtw, const float* __restrict__ dtb,
    const float* __restrict__ alog, const float* __restrict__ Dsp, float* __restrict__ Y){
  int bid = blockIdx.x; int s = bid & 63; int k = (bid >> 6) & 3; int b = bid >> 8;
  int c = threadIdx.x; int bk = b*4 + k;
  __shared__ float sdl[384];
  __shared__ float sB[16][64];
  __shared__ float sC[16][64];
  size_t dbase = (size_t)(bk*64 + s)*384;
  for (int j = c; j < 384; j += 192) sdl[j] = dlsb[dbase + j];
  for (int j = c; j < 1024; j += 192){ int n = j >> 6, i = j & 63;
    size_t o = ((size_t)bk*16 + n)*4096 + (s << 6) + i;
    sB[n][i] = Bsb[o]; sC[n][i] = Csb[o]; }
  __syncthreads();
  float A[16], h[16];
  const float* arow = alog + ((size_t)k*192 + c)*16;
  bool fast = true;
  #pragma unroll
  for (int n = 0; n < 16; n++){
    A[n] = -__expf(arow[n]);
    if (fabsf(A[n] + (float)(n+1)) > 1e-3f) fast = false;
  }
  size_t hbase = ((size_t)(bk*64 + s)*16)*192 + c;
  #pragma unroll
  for (int n = 0; n < 16; n++) h[n] = hinb[hbase + (size_t)n*192];
  float dw[6];
  #pragma unroll
  for (int r = 0; r < 6; r++) dw[r] = dtw[((size_t)k*192 + c)*6 + r];
  float db = dtb[k*192 + c];
  float Dc = Dsp[k*192 + c];
  const float* xrow = xsb + ((size_t)bk*4096 + (s << 6))*192 + c;
  float* Yk = Y + (((size_t)bk*4096 + (s << 6))*192) + c;
  if (fast){
    for (int i = 0; i < 64; i++){
      float u = xrow[(size_t)i*192];
      float acc = db;
      #pragma unroll
      for (int r = 0; r < 6; r++) acc += sdl[i*6 + r]*dw[r];
      float ec = __expf(fminf(acc, 80.f));
      float dl = __logf(1.f + ec);
      float e1 = __builtin_amdgcn_rcpf(1.f + ec);
      float du = dl*u;
      float e = 1.f;
      float y = 0.f;
      #pragma unroll
      for (int n = 0; n < 16; n++){
        e *= e1;
        h[n] = h[n]*e + du*sB[n][i];
        y += h[n]*sC[n][i];
      }
      Yk[(size_t)i*192] = y + u*Dc;
    }
  } else {
    for (int i = 0; i < 64; i++){
      float u = xrow[(size_t)i*192];
      float acc = db;
      #pragma unroll
      for (int r = 0; r < 6; r++) acc += sdl[i*6 + r]*dw[r];
      float ec = __expf(fminf(acc, 80.f));
      float dl = __logf(1.f + ec);
      float du = dl*u;
      float y = 0.f;
      #pragma unroll
      for (int n = 0; n < 16; n++){
        float e = __expf(dl*A[n]);
        h[n] = h[n]*e + du*sB[n][i];
        y += h[n]*sC[n][i];
      }
      Yk[(size_t)i*192] = y + u*Dc;
    }
  }
}

// ------------------------------------------------ K13b: scan phase C — atomic fallback
__global__ __launch_bounds__(192) void k_scanC_atom(const float* __restrict__ xsb,
    const float* __restrict__ dlsb, const float* __restrict__ Bsb, const float* __restrict__ Csb,
    const float* __restrict__ hinb, const float* __restrict__ dtw, const float* __restrict__ dtb,
    const float* __restrict__ alog, const float* __restrict__ Dsp, float* __restrict__ yb){
  int bid = blockIdx.x; int s = bid & 63; int k = (bid >> 6) & 3; int b = bid >> 8;
  int c = threadIdx.x; int bk = b*4 + k;
  __shared__ float sdl[384];
  __shared__ float sB[16][64];
  __shared__ float sC[16][64];
  size_t dbase = (size_t)(bk*64 + s)*384;
  for (int j = c; j < 384; j += 192) sdl[j] = dlsb[dbase + j];
  for (int j = c; j < 1024; j += 192){ int n = j >> 6, i = j & 63;
    size_t o = ((size_t)bk*16 + n)*4096 + (s << 6) + i;
    sB[n][i] = Bsb[o]; sC[n][i] = Csb[o]; }
  __syncthreads();
  float A[16], h[16];
  const float* arow = alog + ((size_t)k*192 + c)*16;
  bool fast = true;
  #pragma unroll
  for (int n = 0; n < 16; n++){
    A[n] = -__expf(arow[n]);
    if (fabsf(A[n] + (float)(n+1)) > 1e-3f) fast = false;
  }
  size_t hbase = ((size_t)(bk*64 + s)*16)*192 + c;
  #pragma unroll
  for (int n = 0; n < 16; n++) h[n] = hinb[hbase + (size_t)n*192];
  float dw[6];
  #pragma unroll
  for (int r = 0; r < 6; r++) dw[r] = dtw[((size_t)k*192 + c)*6 + r];
  float db = dtb[k*192 + c];
  float Dc = Dsp[k*192 + c];
  const float* xrow = xsb + ((size_t)bk*4096 + (s << 6))*192 + c;
  int p0, pst;
  if (k == 0){ p0 = s << 6;        pst = 1;  }
  else if (k == 1){ p0 = s;        pst = 64; }
  else if (k == 2){ p0 = 4095 - (s << 6); pst = -1; }
  else { p0 = 4095 - s;            pst = -64; }
  for (int i = 0; i < 64; i++){
    float u = xrow[(size_t)i*192];
    float acc = db;
    #pragma unroll
    for (int r = 0; r < 6; r++) acc += sdl[i*6 + r]*dw[r];
    float ec = __expf(fminf(acc, 80.f));
    float dl = __logf(1.f + ec);
    float du = dl*u;
    float y = 0.f;
    if (fast){
      float e1 = __builtin_amdgcn_rcpf(1.f + ec);
      float e = 1.f;
      #pragma unroll
      for (int n = 0; n < 16; n++){
        e *= e1;
        h[n] = h[n]*e + du*sB[n][i];
        y += h[n]*sC[n][i];
      }
    } else {
      #pragma unroll
      for (int n = 0; n < 16; n++){
        float e = __expf(dl*A[n]);
        h[n] = h[n]*e + du*sB[n][i];
        y += h[n]*sC[n][i];
      }
    }
    y += u*Dc;
    atomicAdd(&yb[((size_t)b*4096 + p0 + pst*i)*192 + c], y);
  }
}

// ------------------------------------------------ K14b: symmetry enhance (atomic path)
__global__ __launch_bounds__(256) void k_enh(const float* __restrict__ yb,
    const float* __restrict__ symw, float* __restrict__ yfb){
  int id = blockIdx.x*256 + threadIdx.x;
  int c = id % 192; int rest = id / 192; int l = rest & 4095; int b = rest >> 12;
  int w = l & 63; int lr = (l | 63) - w;
  float v  = yb[id];
  float vr = yb[(((size_t)b << 12) + lr)*192 + c];
  float wg = 1.f/(1.f + __expf(-symw[0]));
  float enh = v*(1.f - wg) + 0.5f*(v + vr)*wg;
  yfb[id] = v + 0.2f*enh;
}

// ------------------------------------------------ K15a (fused, bigws): gather scan-order Y + enh + LN + out_proj
__global__ __launch_bounds__(256) void k_final_comb(const float* __restrict__ Y,
    const float* __restrict__ symw, const float* __restrict__ zT,
    const float* __restrict__ g, const float* __restrict__ bta,
    const float* __restrict__ opw, const float* __restrict__ x, float* __restrict__ out){
  int og = blockIdx.x & 1; int lt = (blockIdx.x >> 1) & 127; int b = blockIdx.x >> 8;
  int l0 = lt << 5;
  __shared__ float sv[32][193];
  __shared__ float wt[192*48];
  __shared__ float sg[192], sb2[192];
  __shared__ float smu[32], srs[32];
  int tid = threadIdx.x;
  const size_t S = (size_t)4096*192;
  float wg = 1.f/(1.f + __expf(-symw[0]));
  for (int idx = tid; idx < 6144; idx += 256){
    int r = idx/192, cc = idx - r*192;
    int l = l0 + r;
    int w = l & 63, hh2 = l >> 6;
    int lr  = (l & ~63) | (63 - w);
    int p1  = (w << 6) | hh2;             // dir1 scan pos of l
    int p1r = ((63 - w) << 6) | hh2;      // dir1 scan pos of lr
    size_t base = (size_t)(b*4)*S + cc;
    float v  = Y[base + (size_t)l*192]
             + Y[base + S + (size_t)p1*192]
             + Y[base + 2*S + (size_t)(4095 - l)*192]
             + Y[base + 3*S + (size_t)(4095 - p1)*192];
    float vr = Y[base + (size_t)lr*192]
             + Y[base + S + (size_t)p1r*192]
             + Y[base + 2*S + (size_t)(4095 - lr)*192]
             + Y[base + 3*S + (size_t)(4095 - p1r)*192];
    float enh = v*(1.f - wg) + 0.5f*(v + vr)*wg;
    sv[r][cc] = v + 0.2f*enh;
  }
  if (tid < 192){ sg[tid] = g[tid]; sb2[tid] = bta[tid]; }
  int o0 = og*48;
  for (int idx = tid; idx < 9216; idx += 256){ int o = idx % 48, c = idx/48;
    wt[c*48 + o] = opw[(size_t)(o0 + o)*192 + c]; }
  __syncthreads();
  if (tid < 32){
    float s1 = 0.f, s2 = 0.f;
    for (int c = 0; c < 192; c++){ float v = sv[tid][c]; s1 += v; s2 += v*v; }
    float mu = s1*(1.0f/192.0f);
    smu[tid] = mu; srs[tid] = rsqrtf(s2*(1.0f/192.0f) - mu*mu + 1e-5f);
  }
  __syncthreads();
  for (int idx = tid; idx < 6144; idx += 256){ int l = idx & 31, c = idx >> 5;
    float zv = zT[((size_t)b*192 + c)*4096 + l0 + l];
    float v = sv[l][c];
    float yn = (v - smu[l])*srs[l]*sg[c] + sb2[c];
    sv[l][c] = yn * (zv/(1.f + __expf(-zv)));
  }
  __syncthreads();
  int l = tid & 31, grp = tid >> 5;
  float acc[6];
  #pragma unroll
  for (int j = 0; j < 6; j++) acc[j] = 0.f;
  for (int c = 0; c < 192; c++){
    float svv = sv[l][c];
    const float* wr = &wt[c*48 + grp*6];
    #pragma unroll
    for (int j = 0; j < 6; j += 2){
      float2 w2 = *(const float2*)&wr[j];
      acc[j]   += svv*w2.x; acc[j+1] += svv*w2.y;
    }
  }
  size_t ob = ((size_t)b*4096 + l0 + l)*96 + o0 + grp*6;
  #pragma unroll
  for (int j = 0; j < 6; j++) acc[j] += x[ob + j];
  #pragma unroll
  for (int j = 0; j < 6; j += 2){
    float2 v2; v2.x = acc[j]; v2.y = acc[j+1];
    *(float2*)&out[ob + j] = v2;
  }
}

// ------------------------------------------------ K15b: fallback
__global__ __launch_bounds__(256) void k_final(const float* __restrict__ yf,
    const float* __restrict__ zT, const float* __restrict__ g, const float* __restrict__ bta,
    const float* __restrict__ opw, const float* __restrict__ x, float* __restrict__ out){
  int og = blockIdx.x & 1; int lt = (blockIdx.x >> 1) & 127; int b = blockIdx.x >> 8;
  int l0 = lt << 5;
  __shared__ float sv[32][193];
  __shared__ float wt[192*48];
  __shared__ float sg[192], sb2[192];
  __shared__ float smu[32], srs[32];
  int tid = threadIdx.x;
  for (int idx = tid; idx < 6144; idx += 256){ int r = idx/192, c = idx - r*192;
    sv[r][c] = yf[((size_t)b*4096 + l0 + r)*192 + c]; }
  if (tid < 192){ sg[tid] = g[tid]; sb2[tid] = bta[tid]; }
  int o0 = og*48;
  for (int idx = tid; idx < 9216; idx += 256){ int o = idx % 48, c = idx/48;
    wt[c*48 + o] = opw[(size_t)(o0 + o)*192 + c]; }
  __syncthreads();
  if (tid < 32){
    float s1 = 0.f, s2 = 0.f;
    for (int c = 0; c < 192; c++){ float v = sv[tid][c]; s1 += v; s2 += v*v; }
    float mu = s1*(1.0f/192.0f);
    smu[tid] = mu; srs[tid] = rsqrtf(s2*(1.0f/192.0f) - mu*mu + 1e-5f);
  }
  __syncthreads();
  for (int idx = tid; idx < 6144; idx += 256){ int l = idx & 31, c = idx >> 5;
    float zv = zT[((size_t)b*192 + c)*4096 + l0 + l];
    float v = sv[l][c];
    float yn = (v - smu[l])*srs[l]*sg[c] + sb2[c];
    sv[l][c] = yn * (zv/(1.f + __expf(-zv)));
  }
  __syncthreads();
  int l = tid & 31, grp = tid >> 5;
  float acc[6];
  #pragma unroll
  for (int j = 0; j < 6; j++) acc[j] = 0.f;
  for (int c = 0; c < 192; c++){
    float svv = sv[l][c];
    const float* wr = &wt[c*48 + grp*6];
    #pragma unroll
    for (int j = 0; j < 6; j += 2){
      float2 w2 = *(const float2*)&wr[j];
      acc[j]   += svv*w2.x; acc[j+1] += svv*w2.y;
    }
  }
  size_t ob = ((size_t)b*4096 + l0 + l)*96 + o0 + grp*6;
  #pragma unroll
  for (int j = 0; j < 6; j++) acc[j] += x[ob + j];
  #pragma unroll
  for (int j = 0; j < 6; j += 2){
    float2 v2; v2.x = acc[j]; v2.y = acc[j+1];
    *(float2*)&out[ob + j] = v2;
  }
}

// ================================================================ host
extern "C" void kernel_launch(void* const* d_in, const int* in_sizes, int n_in,
                              void* d_out, int out_size, void* d_ws, size_t ws_size,
                              hipStream_t stream){
  (void)in_sizes; (void)n_in; (void)out_size;
  const float* ix   = (const float*)d_in[0];
  const float* ipw  = (const float*)d_in[1];
  const float* fw1  = (const float*)d_in[2];
  const float* fb1  = (const float*)d_in[3];
  const float* fw2  = (const float*)d_in[4];
  const float* fb2  = (const float*)d_in[5];
  const float* ww   = (const float*)d_in[6];
  const float* wb   = (const float*)d_in[7];
  const float* dww  = (const float*)d_in[8];
  const float* dwb  = (const float*)d_in[9];
  const float* symw = (const float*)d_in[10];
  const float* xpw  = (const float*)d_in[11];
  const float* dtw  = (const float*)d_in[12];
  const float* dtb  = (const float*)d_in[13];
  const float* alog = (const float*)d_in[14];
  const float* Dsp  = (const float*)d_in[15];
  const float* ong  = (const float*)d_in[16];
  const float* onb  = (const float*)d_in[17];
  const float* opw  = (const float*)d_in[18];
  const float* rmsw = (const float*)d_in[19];

  float* W = (float*)d_ws;
  const size_t SZ_BLC = 3145728, SZ_F = 1622016, SZ_H = 786432;
  float* zT  = W;
  float* ab  = zT + SZ_BLC;
  float* R0  = ab + SZ_BLC;
  // phase 1
  float* xc    = R0;
  float* fre   = xc  + SZ_BLC;
  float* fim   = fre + SZ_F;
  float* fab   = fim + SZ_F;
  float* mb    = fab + SZ_F;
  float* llb   = mb  + SZ_F;
  float* lhb   = llb + SZ_H;
  float* wnew  = lhb + 3*SZ_H;
  unsigned short* wqb2 = (unsigned short*)(wnew + 2359296);
  // phase 2
  float* Bsb  = R0;
  float* Csb  = Bsb + 1048576;
  float* dlsb = Csb + 1048576;
  float* xsb  = dlsb + 393216;
  float* Pb   = xsb + 12582912;
  float* aT   = Pb;
  float* Qb   = Pb + SZ_BLC;
  float* Yb   = Qb;                  // scan-order Y [bk][iscan][c]
  float* ybA  = Qb + SZ_BLC;
  float* yfb  = xsb;

  const size_t NEED_BIG = (size_t)(6291456 + 30801920) * 4;
  bool bigws = (ws_size >= NEED_BIG);

  hipLaunchKernelGGL(k_rms_inproj, dim3(2048),   dim3(256), 0, stream, ix, rmsw, ipw, xc, zT);
  hipLaunchKernelGGL(k_dft_fwd,    dim3(4*192),  dim3(256), 0, stream, xc, fre, fim, fab,
                     llb, lhb, lhb + SZ_H, lhb + 2*SZ_H);
  hipLaunchKernelGGL(k_cvt_w,      dim3(1296),   dim3(256), 0, stream, ww, wqb2);
  hipLaunchKernelGGL(k_cmix1,      dim3(864),    dim3(256), 0, stream, fab, fw1, fb1, mb);
  hipLaunchKernelGGL(k_cmix2,      dim3(864),    dim3(256), 0, stream, mb, fw2, fb2, fre, fim, fab);
  hipLaunchKernelGGL(k_wconv_mfma, dim3(576),    dim3(256), 0, stream, lhb, wqb2, wnew);
  hipLaunchKernelGGL(k_ifwd,       dim3(768),    dim3(256), 0, stream, fre, fim, xc, llb, wnew, wb, dww, dwb, ab, aT);
  hipLaunchKernelGGL(k_xproj,      dim3(1024),   dim3(256), 0, stream, ab, aT, xpw, Bsb, Csb, dlsb, xsb);
  hipLaunchKernelGGL(k_scanA,      dim3(1024),   dim3(192), 0, stream, xsb, dlsb, Bsb, dtw, dtb, alog, Pb, Qb);
  hipLaunchKernelGGL(k_scanB,      dim3(192),    dim3(256), 0, stream, Pb, Qb);
  if (bigws){
    hipLaunchKernelGGL(k_scanC_buf,  dim3(1024), dim3(192), 0, stream, xsb, dlsb, Bsb, Csb, Pb, dtw, dtb, alog, Dsp, Yb);
    hipLaunchKernelGGL(k_final_comb, dim3(1024), dim3(256), 0, stream, Yb, symw, zT, ong, onb, opw, ix, (float*)d_out);
  } else {
    hipLaunchKernelGGL(k_zero,       dim3(12288), dim3(256), 0, stream, ybA, (int)SZ_BLC);
    hipLaunchKernelGGL(k_scanC_atom, dim3(1024),  dim3(192), 0, stream, xsb, dlsb, Bsb, Csb, Pb, dtw, dtb, alog, Dsp, ybA);
    hipLaunchKernelGGL(k_enh,        dim3(12288), dim3(256), 0, stream, ybA, symw, yfb);
    hipLaunchKernelGGL(k_final,      dim3(1024),  dim3(256), 0, stream, yfb, zT, ong, onb, opw, ix, (float*)d_out);
  }
}